// Round 1
// baseline (2121.966 us; speedup 1.0000x reference)
//
#include <hip/hip_runtime.h>
#include <math.h>

#define HF 100
#define WFD 160
#define CIN 512
#define CONV_C 512
#define A_ANCH 9
#define NPIX (HF*WFD)           // 16000
#define NBOX (NPIX*A_ANCH)      // 144000
#define PRE_NMS 6000
#define POST_NMS 300
#define NEGV (-1.0e9f)
#define IMG_H 1600.0f
#define IMG_W 2560.0f
#define NHBINS 32768

// ---- workspace layout (units: floats) ----
// Y: 16000x512, then raw scores, nms scores, 4 proposal coord arrays,
// histogram (uint), counters, params, compacted candidate arrays.
static const size_t OY    = 0;
static const size_t ORAW  = OY + (size_t)NPIX * CONV_C;   // 8,192,000
static const size_t ONMS  = ORAW + NBOX;
static const size_t OPY1  = ONMS + NBOX;
static const size_t OPX1  = OPY1 + NBOX;
static const size_t OPY2  = OPX1 + NBOX;
static const size_t OPX2  = OPY2 + NBOX;
static const size_t OHIST = OPX2 + NBOX;                  // 32768 uints
static const size_t OCNT  = OHIST + NHBINS;               // 2 ints
static const size_t OPAR  = OCNT + 2;                     // 2 ints (bin, need)
static const size_t OCS   = OPAR + 2;                     // 6000
static const size_t OCY1  = OCS + PRE_NMS;
static const size_t OCX1  = OCY1 + PRE_NMS;
static const size_t OCY2  = OCX1 + PRE_NMS;
static const size_t OCX2  = OCY2 + PRE_NMS;

// ============================================================
// Kernel 1: 3x3 conv 512->512 + bias + ReLU, fp32, SAME padding.
// GEMM view per (dy,dx): Y[16000x512] += Xshift[16000x512] * W[512x512]
// Tile: 128 pixels x 128 oc, BK=8. 256 threads, 8x8 register blocking.
// ============================================================
__global__ __launch_bounds__(256) void conv3x3_relu(
    const float* __restrict__ X, const float* __restrict__ W1,
    const float* __restrict__ b1, float* __restrict__ Y)
{
    __shared__ float As[8][128];   // [kk][pixel]
    __shared__ float Bs[8][128];   // [kk][oc]

    const int tid = threadIdx.x;
    const int pm0 = blockIdx.x * 128;
    const int oc0 = blockIdx.y * 128;

    // A staging: thread -> (pixel ai, kk base ak), one float4 per stage
    const int ai = tid >> 1;
    const int ak = (tid & 1) * 4;
    const int p  = pm0 + ai;
    const int pr = p / WFD;
    const int pc = p % WFD;

    // B staging: thread -> (kk bk, col bj), one float4 per stage
    const int bk = tid >> 5;
    const int bj = (tid & 31) * 4;

    const int tx = tid & 15;
    const int ty = tid >> 4;

    float acc[8][8];
    #pragma unroll
    for (int j = 0; j < 8; ++j) {
        const float bv = b1[oc0 + tx * 8 + j];
        #pragma unroll
        for (int i = 0; i < 8; ++i) acc[i][j] = bv;
    }

    for (int dydx = 0; dydx < 9; ++dydx) {
        const int dy = dydx / 3 - 1;
        const int dx = dydx % 3 - 1;
        const int rr = pr + dy;
        const int cc = pc + dx;
        const bool inb = (rr >= 0) && (rr < HF) && (cc >= 0) && (cc < WFD);
        const float* xrow  = X + ((size_t)(rr * WFD + cc)) * CIN;
        const float* wbase = W1 + (size_t)dydx * CIN * CONV_C + oc0;

        for (int k0 = 0; k0 < CIN; k0 += 8) {
            float4 av = make_float4(0.f, 0.f, 0.f, 0.f);
            if (inb) av = *(const float4*)(xrow + k0 + ak);
            const float4 bv = *(const float4*)(wbase + (size_t)(k0 + bk) * CONV_C + bj);

            __syncthreads();   // previous-stage reads complete
            As[ak + 0][ai] = av.x;
            As[ak + 1][ai] = av.y;
            As[ak + 2][ai] = av.z;
            As[ak + 3][ai] = av.w;
            *(float4*)&Bs[bk][bj] = bv;
            __syncthreads();

            #pragma unroll
            for (int kk = 0; kk < 8; ++kk) {
                float a0[8], b0[8];
                *(float4*)&a0[0] = *(const float4*)&As[kk][ty * 8];
                *(float4*)&a0[4] = *(const float4*)&As[kk][ty * 8 + 4];
                *(float4*)&b0[0] = *(const float4*)&Bs[kk][tx * 8];
                *(float4*)&b0[4] = *(const float4*)&Bs[kk][tx * 8 + 4];
                #pragma unroll
                for (int i = 0; i < 8; ++i)
                    #pragma unroll
                    for (int j = 0; j < 8; ++j)
                        acc[i][j] = fmaf(a0[i], b0[j], acc[i][j]);
            }
        }
    }

    // ReLU + store
    #pragma unroll
    for (int i = 0; i < 8; ++i) {
        const int prow = pm0 + ty * 8 + i;
        float* yrow = Y + (size_t)prow * CONV_C + oc0 + tx * 8;
        float4 v0, v1;
        v0.x = fmaxf(acc[i][0], 0.f); v0.y = fmaxf(acc[i][1], 0.f);
        v0.z = fmaxf(acc[i][2], 0.f); v0.w = fmaxf(acc[i][3], 0.f);
        v1.x = fmaxf(acc[i][4], 0.f); v1.y = fmaxf(acc[i][5], 0.f);
        v1.z = fmaxf(acc[i][6], 0.f); v1.w = fmaxf(acc[i][7], 0.f);
        *(float4*)(yrow)     = v0;
        *(float4*)(yrow + 4) = v1;
    }
}

// ============================================================
// Kernel 2: 1x1 heads (9 score logits + 36 deltas), softmax, bias,
// anchor decode + clip + valid mask. One thread per pixel.
// Weight reads are wave-uniform -> compiler emits scalar loads.
// ============================================================
__global__ __launch_bounds__(256) void heads_k(
    const float* __restrict__ Y,
    const float* __restrict__ Wc, const float* __restrict__ bc,
    const float* __restrict__ Wr, const float* __restrict__ br,
    const float* __restrict__ anch,
    float* __restrict__ out_scores, float* __restrict__ out_deltas,
    float* __restrict__ rawS, float* __restrict__ nmsS,
    float* __restrict__ pY1, float* __restrict__ pX1,
    float* __restrict__ pY2, float* __restrict__ pX2)
{
    const int p = blockIdx.x * 256 + threadIdx.x;
    if (p >= NPIX) return;

    float ac[9], ar[36];
    #pragma unroll
    for (int a = 0; a < 9; ++a) ac[a] = bc[a];
    #pragma unroll
    for (int j = 0; j < 36; ++j) ar[j] = br[j];

    const float* yrow = Y + (size_t)p * CONV_C;
    for (int k = 0; k < CONV_C; ++k) {
        const float yv = yrow[k];
        const float* wc = Wc + k * 9;
        const float* wr = Wr + k * 36;
        #pragma unroll
        for (int a = 0; a < 9; ++a) ac[a] = fmaf(yv, wc[a], ac[a]);
        #pragma unroll
        for (int j = 0; j < 36; ++j) ar[j] = fmaf(yv, wr[j], ar[j]);
    }

    // softmax over 9
    float m = ac[0];
    #pragma unroll
    for (int a = 1; a < 9; ++a) m = fmaxf(m, ac[a]);
    float s = 0.f, e[9];
    #pragma unroll
    for (int a = 0; a < 9; ++a) { e[a] = expf(ac[a] - m); s += e[a]; }
    #pragma unroll
    for (int a = 0; a < 9; ++a) e[a] = e[a] / s;

    #pragma unroll
    for (int a = 0; a < 9; ++a) out_scores[p * 9 + a] = e[a];
    #pragma unroll
    for (int a = 0; a < 9; ++a) {
        float4 dv = make_float4(ar[4*a], ar[4*a+1], ar[4*a+2], ar[4*a+3]);
        *(float4*)(out_deltas + (size_t)p * 36 + 4 * a) = dv;
    }

    // decode + clip + valid
    #pragma unroll
    for (int a = 0; a < 9; ++a) {
        const float4 an = *(const float4*)(anch + (size_t)p * 36 + 4 * a);
        const float d0 = ar[4*a], d1 = ar[4*a+1], d2 = ar[4*a+2], d3 = ar[4*a+3];
        const float cty = an.x + d0 * an.z;
        const float ctx = an.y + d1 * an.w;
        const float szy = an.z * expf(d2);
        const float szx = an.w * expf(d3);
        float y1 = cty - 0.5f * szy;
        float x1 = ctx - 0.5f * szx;
        float y2 = cty + 0.5f * szy;
        float x2 = ctx + 0.5f * szx;
        y1 = fmaxf(y1, 0.f);
        x1 = fmaxf(x1, 0.f);
        y2 = fminf(y2, IMG_H);
        x2 = fminf(x2, IMG_W);
        const bool valid = ((y2 - y1) >= 16.f) && ((x2 - x1) >= 16.f);
        const int idx = p * 9 + a;
        rawS[idx] = e[a];
        nmsS[idx] = valid ? e[a] : NEGV;
        pY1[idx] = y1; pX1[idx] = x1; pY2[idx] = y2; pX2[idx] = x2;
    }
}

// ============================================================
// Kernel 3: histogram of score float-bit buckets (positive floats are
// order-isomorphic to their bit patterns; bin = bits >> 15).
// ============================================================
__global__ void hist_k(const float* __restrict__ rawS, unsigned int* __restrict__ hist)
{
    const int i = blockIdx.x * 256 + threadIdx.x;
    if (i < NBOX) {
        const unsigned int b = __float_as_uint(rawS[i]) >> 15;
        atomicAdd(&hist[b], 1u);
    }
}

// ============================================================
// Kernel 4: find threshold bin b and 'need' (# to take from bin b)
// such that count(bin > b) + need == PRE_NMS.
// ============================================================
__global__ __launch_bounds__(1024) void select_k(const unsigned int* __restrict__ hist,
                                                 int* __restrict__ params)
{
    __shared__ unsigned int ps[1024];
    const int t = threadIdx.x;
    unsigned int sum = 0;
    #pragma unroll 4
    for (int i = 0; i < 32; ++i) sum += hist[t * 32 + i];
    ps[t] = sum;
    __syncthreads();
    if (t == 0) {
        unsigned int run = 0;
        int bin = 0, need = 0;
        for (int c = 1023; c >= 0; --c) {
            if (run + ps[c] >= (unsigned)PRE_NMS) {
                unsigned int cum = run;
                for (int bb = c * 32 + 31; bb >= c * 32; --bb) {
                    const unsigned int h = hist[bb];
                    if (cum + h >= (unsigned)PRE_NMS) {
                        bin = bb; need = PRE_NMS - (int)cum; break;
                    }
                    cum += h;
                }
                break;
            }
            run += ps[c];
        }
        params[0] = bin;
        params[1] = need;
    }
}

// ============================================================
// Kernel 5: compact the top-6000 candidates into dense arrays.
// ============================================================
__global__ void compact_k(const float* __restrict__ rawS, const float* __restrict__ nmsS,
                          const float* __restrict__ pY1, const float* __restrict__ pX1,
                          const float* __restrict__ pY2, const float* __restrict__ pX2,
                          const int* __restrict__ params, int* __restrict__ cnts,
                          float* __restrict__ cS,
                          float* __restrict__ cY1, float* __restrict__ cX1,
                          float* __restrict__ cY2, float* __restrict__ cX2)
{
    const int i = blockIdx.x * 256 + threadIdx.x;
    if (i >= NBOX) return;
    const int b = (int)(__float_as_uint(rawS[i]) >> 15);
    const int bin = params[0];
    const int need = params[1];
    int pos = -1;
    if (b > bin) {
        pos = atomicAdd(&cnts[0], 1);
    } else if (b == bin) {
        const int t = atomicAdd(&cnts[1], 1);
        if (t < need) pos = atomicAdd(&cnts[0], 1);
    }
    if (pos >= 0) {
        cS[pos]  = nmsS[i];
        cY1[pos] = pY1[i]; cX1[pos] = pX1[i];
        cY2[pos] = pY2[i]; cX2[pos] = pX2[i];
    }
}

// ============================================================
// Kernel 6: sequential NMS, 300 iterations, single block of 1024.
// All candidate state lives in registers (6 strided slots/thread).
// ============================================================
__global__ __launch_bounds__(1024) void nms_k(
    const float* __restrict__ cS,
    const float* __restrict__ cY1, const float* __restrict__ cX1,
    const float* __restrict__ cY2, const float* __restrict__ cX2,
    float* __restrict__ outP)
{
    const int T = 1024;
    const int t = threadIdx.x;

    float s[6], y1[6], x1[6], y2[6], x2[6], ar[6];
    #pragma unroll
    for (int sl = 0; sl < 6; ++sl) {
        const int idx = t + sl * T;
        if (idx < PRE_NMS) {
            s[sl]  = cS[idx];
            y1[sl] = cY1[idx]; x1[sl] = cX1[idx];
            y2[sl] = cY2[idx]; x2[sl] = cX2[idx];
            ar[sl] = (y2[sl] - y1[sl]) * (x2[sl] - x1[sl]);
        } else {
            s[sl] = -2.0e9f;   // below NEGV: never selected
            y1[sl] = x1[sl] = y2[sl] = x2[sl] = ar[sl] = 0.f;
        }
    }

    __shared__ float rs[16];
    __shared__ int   ri[16];
    __shared__ float bb[6];   // y1,x1,y2,x2,area,score
    __shared__ int   bIdx;

    for (int it = 0; it < POST_NMS; ++it) {
        // local argmax
        float bs = -3.0e38f;
        int   bi = 0;
        #pragma unroll
        for (int sl = 0; sl < 6; ++sl) {
            if (s[sl] > bs) { bs = s[sl]; bi = t + sl * T; }
        }
        // wave reduce (64 lanes)
        #pragma unroll
        for (int off = 32; off > 0; off >>= 1) {
            const float os = __shfl_down(bs, off, 64);
            const int   oi = __shfl_down(bi, off, 64);
            if (os > bs) { bs = os; bi = oi; }
        }
        if ((t & 63) == 0) { rs[t >> 6] = bs; ri[t >> 6] = bi; }
        __syncthreads();
        if (t == 0) {
            float fbs = rs[0]; int fbi = ri[0];
            #pragma unroll
            for (int w = 1; w < 16; ++w)
                if (rs[w] > fbs) { fbs = rs[w]; fbi = ri[w]; }
            bb[5] = fbs; bIdx = fbi;
        }
        __syncthreads();
        const int   best   = bIdx;
        const float bscore = bb[5];
        const bool  ok     = bscore > (NEGV * 0.5f);

        if ((best & (T - 1)) == t) {   // owner publishes box, retires entry
            const int sl = best >> 10;
            bb[0] = y1[sl]; bb[1] = x1[sl]; bb[2] = y2[sl]; bb[3] = x2[sl]; bb[4] = ar[sl];
            s[sl] = NEGV;
            float4 o = ok ? make_float4(y1[sl], x1[sl], y2[sl], x2[sl])
                          : make_float4(0.f, 0.f, 0.f, 0.f);
            *(float4*)(outP + 4 * it) = o;
        }
        __syncthreads();

        if (ok) {
            const float by1 = bb[0], bx1 = bb[1], by2 = bb[2], bx2 = bb[3], bar = bb[4];
            #pragma unroll
            for (int sl = 0; sl < 6; ++sl) {
                const float iy1 = fmaxf(y1[sl], by1);
                const float ix1 = fmaxf(x1[sl], bx1);
                const float iy2 = fminf(y2[sl], by2);
                const float ix2 = fminf(x2[sl], bx2);
                const float inter = fmaxf(iy2 - iy1, 0.f) * fmaxf(ix2 - ix1, 0.f);
                const float iou = inter / (ar[sl] + bar - inter + 1e-8f);
                if (iou > 0.7f) s[sl] = NEGV;
            }
        }
    }
}

// ============================================================
extern "C" void kernel_launch(void* const* d_in, const int* in_sizes, int n_in,
                              void* d_out, int out_size, void* d_ws, size_t ws_size,
                              hipStream_t stream)
{
    const float* X    = (const float*)d_in[1];   // feature_map
    const float* anch = (const float*)d_in[2];   // anchor_map
    const float* W1   = (const float*)d_in[3];
    const float* b1   = (const float*)d_in[4];
    const float* Wc   = (const float*)d_in[5];
    const float* bc   = (const float*)d_in[6];
    const float* Wr   = (const float*)d_in[7];
    const float* br   = (const float*)d_in[8];
    // d_in[0]=image (shape only: 1600x2560), d_in[9]=training (0)

    float* out = (float*)d_out;
    float* ws  = (float*)d_ws;

    float* Y    = ws + OY;
    float* rawS = ws + ORAW;
    float* nmsS = ws + ONMS;
    float* pY1  = ws + OPY1;
    float* pX1  = ws + OPX1;
    float* pY2  = ws + OPY2;
    float* pX2  = ws + OPX2;
    unsigned int* hist = (unsigned int*)(ws + OHIST);
    int* cnts   = (int*)(ws + OCNT);
    int* params = (int*)(ws + OPAR);
    float* cS   = ws + OCS;
    float* cY1  = ws + OCY1;
    float* cX1  = ws + OCX1;
    float* cY2  = ws + OCY2;
    float* cX2  = ws + OCX2;

    float* out_scores = out;                 // 144000
    float* out_deltas = out + NBOX;          // 576000
    float* out_props  = out + (size_t)NBOX * 5;  // offset 720000, 1200 floats

    // zero histogram + atomic counters
    hipMemsetAsync(hist, 0, (NHBINS + 2) * sizeof(unsigned int), stream);

    conv3x3_relu<<<dim3(125, 4), 256, 0, stream>>>(X, W1, b1, Y);

    heads_k<<<(NPIX + 255) / 256, 256, 0, stream>>>(
        Y, Wc, bc, Wr, br, anch,
        out_scores, out_deltas, rawS, nmsS, pY1, pX1, pY2, pX2);

    hist_k<<<(NBOX + 255) / 256, 256, 0, stream>>>(rawS, hist);

    select_k<<<1, 1024, 0, stream>>>(hist, params);

    compact_k<<<(NBOX + 255) / 256, 256, 0, stream>>>(
        rawS, nmsS, pY1, pX1, pY2, pX2, params, cnts, cS, cY1, cX1, cY2, cX2);

    nms_k<<<1, 1024, 0, stream>>>(cS, cY1, cX1, cY2, cX2, out_props);
}

// Round 4
// 1284.437 us; speedup vs baseline: 1.6521x; 1.6521x over previous
//
#include <hip/hip_runtime.h>
#include <math.h>

#define HF 100
#define WFD 160
#define CIN 512
#define CONV_C 512
#define NPIX (HF*WFD)           // 16000
#define NBOX (NPIX*9)           // 144000
#define PRE_NMS 6000
#define POST_NMS 300
#define NEGV (-1.0e9f)
#define IMG_H 1600.0f
#define IMG_W 2560.0f
#define NHBINS 32768

// padded X: 102 rows x 162 cols x 512 ch
#define PR 102
#define PC 162
#define NPAD ((size_t)PR*PC*512)   // 8,460,288 elems

typedef __attribute__((ext_vector_type(8))) _Float16 half8;
typedef __attribute__((ext_vector_type(4))) float floatx4;

__device__ __forceinline__ unsigned short f2h_hi(float x) {
    _Float16 h = (_Float16)x;
    return __builtin_bit_cast(unsigned short, h);
}
__device__ __forceinline__ unsigned short f2h_lo(float x, unsigned short hbits) {
    _Float16 h = __builtin_bit_cast(_Float16, hbits);
    _Float16 l = (_Float16)((x - (float)h) * 2048.0f);   // scaled residual: stays normal
    return __builtin_bit_cast(unsigned short, l);
}

#define GLL16(g, l) __builtin_amdgcn_global_load_lds( \
    (const __attribute__((address_space(1))) void*)(g), \
    (__attribute__((address_space(3))) void*)(l), 16, 0, 0)

// ---- workspace layout (units: floats) ----
static const size_t OY    = 0;                              // 8,192,000
static const size_t OXH   = OY + (size_t)NPIX * CONV_C;     // fp16, NPAD elems
static const size_t OXL   = OXH + NPAD / 2;
static const size_t OWH   = OXL + NPAD / 2;                 // fp16 [9][n=512][k=512]
static const size_t OWL   = OWH + (size_t)9*512*512/2;
static const size_t ORAW  = OWL + (size_t)9*512*512/2;
static const size_t ONMS  = ORAW + NBOX;
static const size_t OPY1  = ONMS + NBOX;
static const size_t OPX1  = OPY1 + NBOX;
static const size_t OPY2  = OPX1 + NBOX;
static const size_t OPX2  = OPY2 + NBOX;
static const size_t OHIST = OPX2 + NBOX;                    // 32768 uints
static const size_t OCNT  = OHIST + NHBINS;                 // 2 ints
static const size_t OPAR  = OCNT + 2;                       // 2 ints
static const size_t OCS   = OPAR + 2;                       // 6000
static const size_t OCY1  = OCS + PRE_NMS;
static const size_t OCX1  = OCY1 + PRE_NMS;
static const size_t OCY2  = OCX1 + PRE_NMS;
static const size_t OCX2  = OCY2 + PRE_NMS;

// ============================================================
// split X (fp32) -> padded fp16 hi + scaled-lo
// ============================================================
__global__ __launch_bounds__(256) void split_x(
    const float* __restrict__ X,
    unsigned short* __restrict__ Xh, unsigned short* __restrict__ Xl)
{
    const int idx = blockIdx.x * 256 + threadIdx.x;     // 0..2,048,000-1
    const int p = idx >> 7;
    const int kq = (idx & 127) * 4;
    const float4 v = *(const float4*)(X + (size_t)p * 512 + kq);
    const int r = p / WFD, c = p % WFD;
    const size_t dst = ((size_t)(r + 1) * PC + (c + 1)) * 512 + kq;
    float vv[4] = { v.x, v.y, v.z, v.w };
    unsigned short h[4], lo[4];
    #pragma unroll
    for (int u = 0; u < 4; ++u) {
        h[u]  = f2h_hi(vv[u]);
        lo[u] = f2h_lo(vv[u], h[u]);
    }
    uint2 ph, pl;
    ph.x = (unsigned)h[0]  | ((unsigned)h[1]  << 16);
    ph.y = (unsigned)h[2]  | ((unsigned)h[3]  << 16);
    pl.x = (unsigned)lo[0] | ((unsigned)lo[1] << 16);
    pl.y = (unsigned)lo[2] | ((unsigned)lo[3] << 16);
    *(uint2*)(Xh + dst) = ph;
    *(uint2*)(Xl + dst) = pl;
}

// ============================================================
// split + transpose W1 [dydx][k][n] fp32 -> Wh/Wl [dydx][n][k] fp16
// ============================================================
__global__ __launch_bounds__(256) void split_w(
    const float* __restrict__ W1,
    unsigned short* __restrict__ Wh, unsigned short* __restrict__ Wl)
{
    __shared__ unsigned short Lh[64 * 64];
    __shared__ unsigned short Ll[64 * 64];
    const int t = threadIdx.x;
    const int dydx = blockIdx.x >> 6;
    const int rem  = blockIdx.x & 63;
    const int k0 = (rem >> 3) * 64, n0 = (rem & 7) * 64;

    #pragma unroll
    for (int i = 0; i < 4; ++i) {
        const int f = t + 256 * i;            // 0..1023
        const int row = f >> 4;               // k within tile
        const int cp  = (f & 15) * 4;         // n part
        const float4 v = *(const float4*)(W1 + ((size_t)(dydx * 512 + k0 + row)) * 512 + n0 + cp);
        float vv[4] = { v.x, v.y, v.z, v.w };
        #pragma unroll
        for (int u = 0; u < 4; ++u) {
            const unsigned short h = f2h_hi(vv[u]);
            Lh[(cp + u) * 64 + row] = h;
            Ll[(cp + u) * 64 + row] = f2h_lo(vv[u], h);
        }
    }
    __syncthreads();
    const int n  = t >> 2;
    const int kp = (t & 3) * 16;
    const size_t gbase = ((size_t)(dydx * 512 + n0 + n)) * 512 + k0 + kp;
    *(uint4*)(Wh + gbase)     = *(const uint4*)(Lh + n * 64 + kp);
    *(uint4*)(Wh + gbase + 8) = *(const uint4*)(Lh + n * 64 + kp + 8);
    *(uint4*)(Wl + gbase)     = *(const uint4*)(Ll + n * 64 + kp);
    *(uint4*)(Wl + gbase + 8) = *(const uint4*)(Ll + n * 64 + kp + 8);
}

// ============================================================
// conv 3x3 512->512, split-fp16 3-pass MFMA, dual accumulator.
// y = (Ah+Al/2048)(Bh+Bl/2048) ~= AhBh + (AlBh + AhBl)/2048
// Tile 128x128, BK=32, GLL16 staging (validated: R2==R3 bitwise).
// ============================================================
__global__ __launch_bounds__(256, 2) void conv_mfma(
    const unsigned short* __restrict__ Xh, const unsigned short* __restrict__ Xl,
    const unsigned short* __restrict__ Wh, const unsigned short* __restrict__ Wl,
    const float* __restrict__ b1, float* __restrict__ Y)
{
    __shared__ alignas(16) unsigned short Ah[128 * 32];
    __shared__ alignas(16) unsigned short Al[128 * 32];
    __shared__ alignas(16) unsigned short Bh[128 * 32];
    __shared__ alignas(16) unsigned short Bl[128 * 32];

    const int tid = threadIdx.x;
    const int w = tid >> 6, l = tid & 63;
    const int wy = w >> 1, wx = w & 1;
    const int pm0 = blockIdx.x * 128, oc0 = blockIdx.y * 128;

    // staging: wave w covers tile rows [w*32, w*32+32), 2 issues of 16 rows
    int aoff[2], boff[2], ldsOff[2];
    #pragma unroll
    for (int i = 0; i < 2; ++i) {
        const int m = w * 32 + i * 16 + (l >> 2);
        const int p = pm0 + m;
        const int r = p / WFD, c = p % WFD;
        aoff[i] = ((r + 1) * PC + (c + 1)) * 512 + (l & 3) * 8;
        boff[i] = (oc0 + m) * 512 + (l & 3) * 8;
        ldsOff[i] = (w * 32 + i * 16) * 32;
    }

    // fragment LDS offsets (ushort units)
    int afrag[4], bfrag[4];
    #pragma unroll
    for (int i = 0; i < 4; ++i) {
        afrag[i] = (wy * 64 + i * 16 + (l & 15)) * 32 + (l >> 4) * 8;
        bfrag[i] = (wx * 64 + i * 16 + (l & 15)) * 32 + (l >> 4) * 8;
    }

    floatx4 acc[4][4], accL[4][4];
    #pragma unroll
    for (int j = 0; j < 4; ++j) {
        const float bv = b1[oc0 + wx * 64 + j * 16 + (l & 15)];
        #pragma unroll
        for (int i = 0; i < 4; ++i) {
            acc[i][j][0] = bv; acc[i][j][1] = bv; acc[i][j][2] = bv; acc[i][j][3] = bv;
            accL[i][j][0] = 0.f; accL[i][j][1] = 0.f; accL[i][j][2] = 0.f; accL[i][j][3] = 0.f;
        }
    }

    for (int dydx = 0; dydx < 9; ++dydx) {
        const int dy = dydx / 3 - 1, dx = dydx % 3 - 1;
        const int dA = (dy * PC + dx) * 512;
        const int dB = dydx * (512 * 512);
        for (int k0 = 0; k0 < 512; k0 += 32) {
            __syncthreads();
            #pragma unroll
            for (int i = 0; i < 2; ++i) {
                GLL16(Xh + aoff[i] + dA + k0, Ah + ldsOff[i]);
                GLL16(Xl + aoff[i] + dA + k0, Al + ldsOff[i]);
                GLL16(Wh + boff[i] + dB + k0, Bh + ldsOff[i]);
                GLL16(Wl + boff[i] + dB + k0, Bl + ldsOff[i]);
            }
            __syncthreads();
            half8 fah[4], fal[4], fbh[4], fbl[4];
            #pragma unroll
            for (int i = 0; i < 4; ++i) {
                fah[i] = *(const half8*)(Ah + afrag[i]);
                fal[i] = *(const half8*)(Al + afrag[i]);
                fbh[i] = *(const half8*)(Bh + bfrag[i]);
                fbl[i] = *(const half8*)(Bl + bfrag[i]);
            }
            #pragma unroll
            for (int i = 0; i < 4; ++i)
                #pragma unroll
                for (int j = 0; j < 4; ++j) {
                    acc[i][j]  = __builtin_amdgcn_mfma_f32_16x16x32_f16(fah[i], fbh[j], acc[i][j], 0, 0, 0);
                    accL[i][j] = __builtin_amdgcn_mfma_f32_16x16x32_f16(fal[i], fbh[j], accL[i][j], 0, 0, 0);
                    accL[i][j] = __builtin_amdgcn_mfma_f32_16x16x32_f16(fah[i], fbl[j], accL[i][j], 0, 0, 0);
                }
        }
    }

    // epilogue: combine + ReLU + store. C/D: col=lane&15, row=(lane>>4)*4+reg
    #pragma unroll
    for (int i = 0; i < 4; ++i) {
        const int row0 = pm0 + wy * 64 + i * 16 + (l >> 4) * 4;
        #pragma unroll
        for (int j = 0; j < 4; ++j) {
            const int col = oc0 + wx * 64 + j * 16 + (l & 15);
            #pragma unroll
            for (int r = 0; r < 4; ++r) {
                const float yv = acc[i][j][r] + accL[i][j][r] * 4.8828125e-4f;  // 1/2048
                Y[(size_t)(row0 + r) * 512 + col] = fmaxf(yv, 0.f);
            }
        }
    }
}

// ============================================================
// heads: R1's exact known-good version (thread-per-pixel, scalar).
// ============================================================
__global__ __launch_bounds__(256) void heads_k(
    const float* __restrict__ Y,
    const float* __restrict__ Wc, const float* __restrict__ bc,
    const float* __restrict__ Wr, const float* __restrict__ br,
    const float* __restrict__ anch,
    float* __restrict__ out_scores, float* __restrict__ out_deltas,
    float* __restrict__ rawS, float* __restrict__ nmsS,
    float* __restrict__ pY1, float* __restrict__ pX1,
    float* __restrict__ pY2, float* __restrict__ pX2)
{
    const int p = blockIdx.x * 256 + threadIdx.x;
    if (p >= NPIX) return;

    float ac[9], ar[36];
    #pragma unroll
    for (int a = 0; a < 9; ++a) ac[a] = bc[a];
    #pragma unroll
    for (int j = 0; j < 36; ++j) ar[j] = br[j];

    const float* yrow = Y + (size_t)p * CONV_C;
    for (int k = 0; k < CONV_C; ++k) {
        const float yv = yrow[k];
        const float* wc = Wc + k * 9;
        const float* wr = Wr + k * 36;
        #pragma unroll
        for (int a = 0; a < 9; ++a) ac[a] = fmaf(yv, wc[a], ac[a]);
        #pragma unroll
        for (int j = 0; j < 36; ++j) ar[j] = fmaf(yv, wr[j], ar[j]);
    }

    float m = ac[0];
    #pragma unroll
    for (int a = 1; a < 9; ++a) m = fmaxf(m, ac[a]);
    float s = 0.f, e[9];
    #pragma unroll
    for (int a = 0; a < 9; ++a) { e[a] = expf(ac[a] - m); s += e[a]; }
    #pragma unroll
    for (int a = 0; a < 9; ++a) e[a] = e[a] / s;

    #pragma unroll
    for (int a = 0; a < 9; ++a) out_scores[p * 9 + a] = e[a];
    #pragma unroll
    for (int a = 0; a < 9; ++a) {
        float4 dv = make_float4(ar[4*a], ar[4*a+1], ar[4*a+2], ar[4*a+3]);
        *(float4*)(out_deltas + (size_t)p * 36 + 4 * a) = dv;
    }

    #pragma unroll
    for (int a = 0; a < 9; ++a) {
        const float4 an = *(const float4*)(anch + (size_t)p * 36 + 4 * a);
        const float d0 = ar[4*a], d1 = ar[4*a+1], d2 = ar[4*a+2], d3 = ar[4*a+3];
        const float cty = an.x + d0 * an.z;
        const float ctx = an.y + d1 * an.w;
        const float szy = an.z * expf(d2);
        const float szx = an.w * expf(d3);
        float y1 = fmaxf(cty - 0.5f * szy, 0.f);
        float x1 = fmaxf(ctx - 0.5f * szx, 0.f);
        float y2 = fminf(cty + 0.5f * szy, IMG_H);
        float x2 = fminf(ctx + 0.5f * szx, IMG_W);
        const bool valid = ((y2 - y1) >= 16.f) && ((x2 - x1) >= 16.f);
        const int idx = p * 9 + a;
        rawS[idx] = e[a];
        nmsS[idx] = valid ? e[a] : NEGV;
        pY1[idx] = y1; pX1[idx] = x1; pY2[idx] = y2; pX2[idx] = x2;
    }
}

// ============================================================
__global__ void hist_k(const float* __restrict__ rawS, unsigned int* __restrict__ hist)
{
    const int i = blockIdx.x * 256 + threadIdx.x;
    if (i < NBOX) {
        const unsigned int b = __float_as_uint(rawS[i]) >> 15;
        atomicAdd(&hist[b], 1u);
    }
}

__global__ __launch_bounds__(1024) void select_k(const unsigned int* __restrict__ hist,
                                                 int* __restrict__ params)
{
    __shared__ unsigned int ps[1024];
    const int t = threadIdx.x;
    unsigned int sum = 0;
    #pragma unroll 4
    for (int i = 0; i < 32; ++i) sum += hist[t * 32 + i];
    ps[t] = sum;
    __syncthreads();
    if (t == 0) {
        unsigned int run = 0;
        int bin = 0, need = 0;
        for (int c = 1023; c >= 0; --c) {
            if (run + ps[c] >= (unsigned)PRE_NMS) {
                unsigned int cum = run;
                for (int bb = c * 32 + 31; bb >= c * 32; --bb) {
                    const unsigned int h = hist[bb];
                    if (cum + h >= (unsigned)PRE_NMS) { bin = bb; need = PRE_NMS - (int)cum; break; }
                    cum += h;
                }
                break;
            }
            run += ps[c];
        }
        params[0] = bin;
        params[1] = need;
    }
}

__global__ void compact_k(const float* __restrict__ rawS, const float* __restrict__ nmsS,
                          const float* __restrict__ pY1, const float* __restrict__ pX1,
                          const float* __restrict__ pY2, const float* __restrict__ pX2,
                          const int* __restrict__ params, int* __restrict__ cnts,
                          float* __restrict__ cS,
                          float* __restrict__ cY1, float* __restrict__ cX1,
                          float* __restrict__ cY2, float* __restrict__ cX2)
{
    const int i = blockIdx.x * 256 + threadIdx.x;
    if (i >= NBOX) return;
    const int b = (int)(__float_as_uint(rawS[i]) >> 15);
    const int bin = params[0];
    const int need = params[1];
    int pos = -1;
    if (b > bin) {
        pos = atomicAdd(&cnts[0], 1);
    } else if (b == bin) {
        const int t2 = atomicAdd(&cnts[1], 1);
        if (t2 < need) pos = atomicAdd(&cnts[0], 1);
    }
    if (pos >= 0) {
        cS[pos]  = nmsS[i];
        cY1[pos] = pY1[i]; cX1[pos] = pX1[i];
        cY2[pos] = pY2[i]; cX2[pos] = pX2[i];
    }
}

__global__ __launch_bounds__(1024) void nms_k(
    const float* __restrict__ cS,
    const float* __restrict__ cY1, const float* __restrict__ cX1,
    const float* __restrict__ cY2, const float* __restrict__ cX2,
    float* __restrict__ outP)
{
    const int T = 1024;
    const int t = threadIdx.x;

    float s[6], y1[6], x1[6], y2[6], x2[6], ar[6];
    #pragma unroll
    for (int sl = 0; sl < 6; ++sl) {
        const int idx = t + sl * T;
        if (idx < PRE_NMS) {
            s[sl]  = cS[idx];
            y1[sl] = cY1[idx]; x1[sl] = cX1[idx];
            y2[sl] = cY2[idx]; x2[sl] = cX2[idx];
            ar[sl] = (y2[sl] - y1[sl]) * (x2[sl] - x1[sl]);
        } else {
            s[sl] = -2.0e9f;
            y1[sl] = x1[sl] = y2[sl] = x2[sl] = ar[sl] = 0.f;
        }
    }

    __shared__ float rs[16];
    __shared__ int   ri[16];
    __shared__ float bb[6];
    __shared__ int   bIdx;

    for (int it = 0; it < POST_NMS; ++it) {
        float bs = -3.0e38f;
        int   bi = 0;
        #pragma unroll
        for (int sl = 0; sl < 6; ++sl)
            if (s[sl] > bs) { bs = s[sl]; bi = t + sl * T; }
        #pragma unroll
        for (int off = 32; off > 0; off >>= 1) {
            const float os = __shfl_down(bs, off, 64);
            const int   oi = __shfl_down(bi, off, 64);
            if (os > bs) { bs = os; bi = oi; }
        }
        if ((t & 63) == 0) { rs[t >> 6] = bs; ri[t >> 6] = bi; }
        __syncthreads();
        if (t == 0) {
            float fbs = rs[0]; int fbi = ri[0];
            #pragma unroll
            for (int w = 1; w < 16; ++w)
                if (rs[w] > fbs) { fbs = rs[w]; fbi = ri[w]; }
            bb[5] = fbs; bIdx = fbi;
        }
        __syncthreads();
        const int   best   = bIdx;
        const bool  ok     = bb[5] > (NEGV * 0.5f);

        if ((best & (T - 1)) == t) {
            const int sl = best >> 10;
            bb[0] = y1[sl]; bb[1] = x1[sl]; bb[2] = y2[sl]; bb[3] = x2[sl]; bb[4] = ar[sl];
            s[sl] = NEGV;
            float4 o = ok ? make_float4(y1[sl], x1[sl], y2[sl], x2[sl])
                          : make_float4(0.f, 0.f, 0.f, 0.f);
            *(float4*)(outP + 4 * it) = o;
        }
        __syncthreads();

        if (ok) {
            const float by1 = bb[0], bx1 = bb[1], by2 = bb[2], bx2 = bb[3], bar = bb[4];
            #pragma unroll
            for (int sl = 0; sl < 6; ++sl) {
                const float iy1 = fmaxf(y1[sl], by1);
                const float ix1 = fmaxf(x1[sl], bx1);
                const float iy2 = fminf(y2[sl], by2);
                const float ix2 = fminf(x2[sl], bx2);
                const float inter = fmaxf(iy2 - iy1, 0.f) * fmaxf(ix2 - ix1, 0.f);
                const float iou = inter / (ar[sl] + bar - inter + 1e-8f);
                if (iou > 0.7f) s[sl] = NEGV;
            }
        }
    }
}

// ============================================================
extern "C" void kernel_launch(void* const* d_in, const int* in_sizes, int n_in,
                              void* d_out, int out_size, void* d_ws, size_t ws_size,
                              hipStream_t stream)
{
    const float* X    = (const float*)d_in[1];
    const float* anch = (const float*)d_in[2];
    const float* W1   = (const float*)d_in[3];
    const float* b1   = (const float*)d_in[4];
    const float* Wc   = (const float*)d_in[5];
    const float* bc   = (const float*)d_in[6];
    const float* Wr   = (const float*)d_in[7];
    const float* br   = (const float*)d_in[8];

    float* out = (float*)d_out;
    float* ws  = (float*)d_ws;

    float* Y = ws + OY;
    unsigned short* Xh = (unsigned short*)(ws + OXH);
    unsigned short* Xl = (unsigned short*)(ws + OXL);
    unsigned short* Wh = (unsigned short*)(ws + OWH);
    unsigned short* Wl = (unsigned short*)(ws + OWL);
    float* rawS = ws + ORAW;
    float* nmsS = ws + ONMS;
    float* pY1  = ws + OPY1;
    float* pX1  = ws + OPX1;
    float* pY2  = ws + OPY2;
    float* pX2  = ws + OPX2;
    unsigned int* hist = (unsigned int*)(ws + OHIST);
    int* cnts   = (int*)(ws + OCNT);
    int* params = (int*)(ws + OPAR);
    float* cS   = ws + OCS;
    float* cY1  = ws + OCY1;
    float* cX1  = ws + OCX1;
    float* cY2  = ws + OCY2;
    float* cX2  = ws + OCX2;

    float* out_scores = out;
    float* out_deltas = out + NBOX;
    float* out_props  = out + (size_t)NBOX * 5;

    hipMemsetAsync(hist, 0, (NHBINS + 4) * sizeof(unsigned int), stream);
    hipMemsetAsync(Xh, 0, NPAD * sizeof(unsigned short), stream);
    hipMemsetAsync(Xl, 0, NPAD * sizeof(unsigned short), stream);

    split_x<<<8000, 256, 0, stream>>>(X, Xh, Xl);
    split_w<<<576, 256, 0, stream>>>(W1, Wh, Wl);

    conv_mfma<<<dim3(125, 4), 256, 0, stream>>>(Xh, Xl, Wh, Wl, b1, Y);

    heads_k<<<(NPIX + 255) / 256, 256, 0, stream>>>(Y, Wc, bc, Wr, br, anch,
        out_scores, out_deltas, rawS, nmsS, pY1, pX1, pY2, pX2);

    hist_k<<<(NBOX + 255) / 256, 256, 0, stream>>>(rawS, hist);
    select_k<<<1, 1024, 0, stream>>>(hist, params);
    compact_k<<<(NBOX + 255) / 256, 256, 0, stream>>>(
        rawS, nmsS, pY1, pX1, pY2, pX2, params, cnts, cS, cY1, cX1, cY2, cX2);
    nms_k<<<1, 1024, 0, stream>>>(cS, cY1, cX1, cY2, cX2, out_props);
}

// Round 5
// 924.666 us; speedup vs baseline: 2.2948x; 1.3891x over previous
//
#include <hip/hip_runtime.h>
#include <math.h>

#define HF 100
#define WFD 160
#define CIN 512
#define CONV_C 512
#define NPIX (HF*WFD)           // 16000
#define NBOX (NPIX*9)           // 144000
#define PRE_NMS 6000
#define POST_NMS 300
#define NEGV (-1.0e9f)
#define IMG_H 1600.0f
#define IMG_W 2560.0f
#define NHBINS 32768
#define NWORDS 94               // ceil(6000/64)
#define NSORT 6016              // 94*64

// padded X: 102 rows x 162 cols x 512 ch
#define PR 102
#define PC 162
#define NPAD ((size_t)PR*PC*512)   // 8,460,288 elems

typedef __attribute__((ext_vector_type(8))) _Float16 half8;
typedef __attribute__((ext_vector_type(4))) float floatx4;

__device__ __forceinline__ unsigned short f2h_hi(float x) {
    _Float16 h = (_Float16)x;
    return __builtin_bit_cast(unsigned short, h);
}
__device__ __forceinline__ unsigned short f2h_lo(float x, unsigned short hbits) {
    _Float16 h = __builtin_bit_cast(_Float16, hbits);
    _Float16 l = (_Float16)((x - (float)h) * 2048.0f);   // scaled residual: stays normal
    return __builtin_bit_cast(unsigned short, l);
}

#define GLL16(g, l) __builtin_amdgcn_global_load_lds( \
    (const __attribute__((address_space(1))) void*)(g), \
    (__attribute__((address_space(3))) void*)(l), 16, 0, 0)

// ---- workspace layout (units: floats) ----
static const size_t OY    = 0;                              // 8,192,000 (dead after heads_k)
static const size_t OXH   = OY + (size_t)NPIX * CONV_C;     // fp16, NPAD elems
static const size_t OXL   = OXH + NPAD / 2;
static const size_t OWH   = OXL + NPAD / 2;                 // fp16 [9][n=512][k=512]
static const size_t OWL   = OWH + (size_t)9*512*512/2;
static const size_t ORAW  = OWL + (size_t)9*512*512/2;
static const size_t ONMS  = ORAW + NBOX;
static const size_t OPY1  = ONMS + NBOX;
static const size_t OPX1  = OPY1 + NBOX;
static const size_t OPY2  = OPX1 + NBOX;
static const size_t OPX2  = OPY2 + NBOX;
static const size_t OHIST = OPX2 + NBOX;                    // 32768 uints
static const size_t OCNT  = OHIST + NHBINS;                 // 2 ints
static const size_t OPAR  = OCNT + 2;                       // 2 ints
static const size_t OCS   = OPAR + 2;                       // 6000
static const size_t OCY1  = OCS + PRE_NMS;
static const size_t OCX1  = OCY1 + PRE_NMS;
static const size_t OCY2  = OCX1 + PRE_NMS;
static const size_t OCX2  = OCY2 + PRE_NMS;
// sorted arrays + mask OVERLAY the Y region (Y dead after heads_k)
static const size_t OSS   = OY;                             // 6016
static const size_t OSY1  = OSS  + NSORT;
static const size_t OSX1  = OSY1 + NSORT;
static const size_t OSY2  = OSX1 + NSORT;
static const size_t OSX2  = OSY2 + NSORT;
static const size_t OSAR  = OSX2 + NSORT;                   // ends 36,096
static const size_t OMASK = OY + 40000;                     // u64[6016*94] = 1,131,008 floats

// ============================================================
// split X (fp32) -> padded fp16 hi + scaled-lo
// ============================================================
__global__ __launch_bounds__(256) void split_x(
    const float* __restrict__ X,
    unsigned short* __restrict__ Xh, unsigned short* __restrict__ Xl)
{
    const int idx = blockIdx.x * 256 + threadIdx.x;
    const int p = idx >> 7;
    const int kq = (idx & 127) * 4;
    const float4 v = *(const float4*)(X + (size_t)p * 512 + kq);
    const int r = p / WFD, c = p % WFD;
    const size_t dst = ((size_t)(r + 1) * PC + (c + 1)) * 512 + kq;
    float vv[4] = { v.x, v.y, v.z, v.w };
    unsigned short h[4], lo[4];
    #pragma unroll
    for (int u = 0; u < 4; ++u) {
        h[u]  = f2h_hi(vv[u]);
        lo[u] = f2h_lo(vv[u], h[u]);
    }
    uint2 ph, pl;
    ph.x = (unsigned)h[0]  | ((unsigned)h[1]  << 16);
    ph.y = (unsigned)h[2]  | ((unsigned)h[3]  << 16);
    pl.x = (unsigned)lo[0] | ((unsigned)lo[1] << 16);
    pl.y = (unsigned)lo[2] | ((unsigned)lo[3] << 16);
    *(uint2*)(Xh + dst) = ph;
    *(uint2*)(Xl + dst) = pl;
}

// ============================================================
// split + transpose W1 [dydx][k][n] fp32 -> Wh/Wl [dydx][n][k] fp16
// ============================================================
__global__ __launch_bounds__(256) void split_w(
    const float* __restrict__ W1,
    unsigned short* __restrict__ Wh, unsigned short* __restrict__ Wl)
{
    __shared__ unsigned short Lh[64 * 64];
    __shared__ unsigned short Ll[64 * 64];
    const int t = threadIdx.x;
    const int dydx = blockIdx.x >> 6;
    const int rem  = blockIdx.x & 63;
    const int k0 = (rem >> 3) * 64, n0 = (rem & 7) * 64;

    #pragma unroll
    for (int i = 0; i < 4; ++i) {
        const int f = t + 256 * i;
        const int row = f >> 4;
        const int cp  = (f & 15) * 4;
        const float4 v = *(const float4*)(W1 + ((size_t)(dydx * 512 + k0 + row)) * 512 + n0 + cp);
        float vv[4] = { v.x, v.y, v.z, v.w };
        #pragma unroll
        for (int u = 0; u < 4; ++u) {
            const unsigned short h = f2h_hi(vv[u]);
            Lh[(cp + u) * 64 + row] = h;
            Ll[(cp + u) * 64 + row] = f2h_lo(vv[u], h);
        }
    }
    __syncthreads();
    const int n  = t >> 2;
    const int kp = (t & 3) * 16;
    const size_t gbase = ((size_t)(dydx * 512 + n0 + n)) * 512 + k0 + kp;
    *(uint4*)(Wh + gbase)     = *(const uint4*)(Lh + n * 64 + kp);
    *(uint4*)(Wh + gbase + 8) = *(const uint4*)(Lh + n * 64 + kp + 8);
    *(uint4*)(Wl + gbase)     = *(const uint4*)(Ll + n * 64 + kp);
    *(uint4*)(Wl + gbase + 8) = *(const uint4*)(Ll + n * 64 + kp + 8);
}

// ============================================================
// conv 3x3 512->512, split-fp16 3-pass MFMA, dual accumulator (R4, verified).
// ============================================================
__global__ __launch_bounds__(256, 2) void conv_mfma(
    const unsigned short* __restrict__ Xh, const unsigned short* __restrict__ Xl,
    const unsigned short* __restrict__ Wh, const unsigned short* __restrict__ Wl,
    const float* __restrict__ b1, float* __restrict__ Y)
{
    __shared__ alignas(16) unsigned short Ah[128 * 32];
    __shared__ alignas(16) unsigned short Al[128 * 32];
    __shared__ alignas(16) unsigned short Bh[128 * 32];
    __shared__ alignas(16) unsigned short Bl[128 * 32];

    const int tid = threadIdx.x;
    const int w = tid >> 6, l = tid & 63;
    const int wy = w >> 1, wx = w & 1;
    const int pm0 = blockIdx.x * 128, oc0 = blockIdx.y * 128;

    int aoff[2], boff[2], ldsOff[2];
    #pragma unroll
    for (int i = 0; i < 2; ++i) {
        const int m = w * 32 + i * 16 + (l >> 2);
        const int p = pm0 + m;
        const int r = p / WFD, c = p % WFD;
        aoff[i] = ((r + 1) * PC + (c + 1)) * 512 + (l & 3) * 8;
        boff[i] = (oc0 + m) * 512 + (l & 3) * 8;
        ldsOff[i] = (w * 32 + i * 16) * 32;
    }

    int afrag[4], bfrag[4];
    #pragma unroll
    for (int i = 0; i < 4; ++i) {
        afrag[i] = (wy * 64 + i * 16 + (l & 15)) * 32 + (l >> 4) * 8;
        bfrag[i] = (wx * 64 + i * 16 + (l & 15)) * 32 + (l >> 4) * 8;
    }

    floatx4 acc[4][4], accL[4][4];
    #pragma unroll
    for (int j = 0; j < 4; ++j) {
        const float bv = b1[oc0 + wx * 64 + j * 16 + (l & 15)];
        #pragma unroll
        for (int i = 0; i < 4; ++i) {
            acc[i][j][0] = bv; acc[i][j][1] = bv; acc[i][j][2] = bv; acc[i][j][3] = bv;
            accL[i][j][0] = 0.f; accL[i][j][1] = 0.f; accL[i][j][2] = 0.f; accL[i][j][3] = 0.f;
        }
    }

    for (int dydx = 0; dydx < 9; ++dydx) {
        const int dy = dydx / 3 - 1, dx = dydx % 3 - 1;
        const int dA = (dy * PC + dx) * 512;
        const int dB = dydx * (512 * 512);
        for (int k0 = 0; k0 < 512; k0 += 32) {
            __syncthreads();
            #pragma unroll
            for (int i = 0; i < 2; ++i) {
                GLL16(Xh + aoff[i] + dA + k0, Ah + ldsOff[i]);
                GLL16(Xl + aoff[i] + dA + k0, Al + ldsOff[i]);
                GLL16(Wh + boff[i] + dB + k0, Bh + ldsOff[i]);
                GLL16(Wl + boff[i] + dB + k0, Bl + ldsOff[i]);
            }
            __syncthreads();
            half8 fah[4], fal[4], fbh[4], fbl[4];
            #pragma unroll
            for (int i = 0; i < 4; ++i) {
                fah[i] = *(const half8*)(Ah + afrag[i]);
                fal[i] = *(const half8*)(Al + afrag[i]);
                fbh[i] = *(const half8*)(Bh + bfrag[i]);
                fbl[i] = *(const half8*)(Bl + bfrag[i]);
            }
            #pragma unroll
            for (int i = 0; i < 4; ++i)
                #pragma unroll
                for (int j = 0; j < 4; ++j) {
                    acc[i][j]  = __builtin_amdgcn_mfma_f32_16x16x32_f16(fah[i], fbh[j], acc[i][j], 0, 0, 0);
                    accL[i][j] = __builtin_amdgcn_mfma_f32_16x16x32_f16(fal[i], fbh[j], accL[i][j], 0, 0, 0);
                    accL[i][j] = __builtin_amdgcn_mfma_f32_16x16x32_f16(fah[i], fbl[j], accL[i][j], 0, 0, 0);
                }
        }
    }

    #pragma unroll
    for (int i = 0; i < 4; ++i) {
        const int row0 = pm0 + wy * 64 + i * 16 + (l >> 4) * 4;
        #pragma unroll
        for (int j = 0; j < 4; ++j) {
            const int col = oc0 + wx * 64 + j * 16 + (l & 15);
            #pragma unroll
            for (int r = 0; r < 4; ++r) {
                const float yv = acc[i][j][r] + accL[i][j][r] * 4.8828125e-4f;  // 1/2048
                Y[(size_t)(row0 + r) * 512 + col] = fmaxf(yv, 0.f);
            }
        }
    }
}

// ============================================================
// heads: LDS-staged version (verified correct in R2: outputs 0/1 passed)
// ============================================================
__global__ __launch_bounds__(64) void heads_k(
    const float* __restrict__ Y,
    const float* __restrict__ Wc, const float* __restrict__ bc,
    const float* __restrict__ Wr, const float* __restrict__ br,
    const float* __restrict__ anch,
    float* __restrict__ out_scores, float* __restrict__ out_deltas,
    float* __restrict__ rawS, float* __restrict__ nmsS,
    float* __restrict__ pY1, float* __restrict__ pX1,
    float* __restrict__ pY2, float* __restrict__ pX2)
{
    __shared__ float Ys[64 * 17];
    const int t = threadIdx.x;
    const int p0 = blockIdx.x * 64;
    const int p = p0 + t;

    float ac[9], arr[36];
    #pragma unroll
    for (int a = 0; a < 9; ++a) ac[a] = bc[a];
    #pragma unroll
    for (int j = 0; j < 36; ++j) arr[j] = br[j];

    for (int k0 = 0; k0 < 512; k0 += 16) {
        __syncthreads();
        #pragma unroll
        for (int i = 0; i < 4; ++i) {
            const int f = t + 64 * i;
            const int row = f >> 2, part = f & 3;
            const float4 v = *(const float4*)(Y + (size_t)(p0 + row) * 512 + k0 + part * 4);
            float* d = Ys + row * 17 + part * 4;
            d[0] = v.x; d[1] = v.y; d[2] = v.z; d[3] = v.w;
        }
        __syncthreads();
        #pragma unroll 4
        for (int kk = 0; kk < 16; ++kk) {
            const float yv = Ys[t * 17 + kk];
            const int kg = k0 + kk;
            const float* wc = Wc + kg * 9;
            const float* wr = Wr + kg * 36;
            #pragma unroll
            for (int a = 0; a < 9; ++a) ac[a] = fmaf(yv, wc[a], ac[a]);
            #pragma unroll
            for (int j = 0; j < 36; ++j) arr[j] = fmaf(yv, wr[j], arr[j]);
        }
    }

    float m = ac[0];
    #pragma unroll
    for (int a = 1; a < 9; ++a) m = fmaxf(m, ac[a]);
    float s = 0.f, e[9];
    #pragma unroll
    for (int a = 0; a < 9; ++a) { e[a] = expf(ac[a] - m); s += e[a]; }
    #pragma unroll
    for (int a = 0; a < 9; ++a) e[a] = e[a] / s;

    #pragma unroll
    for (int a = 0; a < 9; ++a) out_scores[p * 9 + a] = e[a];
    #pragma unroll
    for (int a = 0; a < 9; ++a)
        *(float4*)(out_deltas + (size_t)p * 36 + 4 * a) =
            make_float4(arr[4*a], arr[4*a+1], arr[4*a+2], arr[4*a+3]);

    #pragma unroll
    for (int a = 0; a < 9; ++a) {
        const float4 an = *(const float4*)(anch + (size_t)p * 36 + 4 * a);
        const float cty = an.x + arr[4*a]   * an.z;
        const float ctx = an.y + arr[4*a+1] * an.w;
        const float szy = an.z * expf(arr[4*a+2]);
        const float szx = an.w * expf(arr[4*a+3]);
        float y1 = fmaxf(cty - 0.5f * szy, 0.f);
        float x1 = fmaxf(ctx - 0.5f * szx, 0.f);
        float y2 = fminf(cty + 0.5f * szy, IMG_H);
        float x2 = fminf(ctx + 0.5f * szx, IMG_W);
        const bool valid = ((y2 - y1) >= 16.f) && ((x2 - x1) >= 16.f);
        const int idx = p * 9 + a;
        rawS[idx] = e[a];
        nmsS[idx] = valid ? e[a] : NEGV;
        pY1[idx] = y1; pX1[idx] = x1; pY2[idx] = y2; pX2[idx] = x2;
    }
}

// ============================================================
__global__ void hist_k(const float* __restrict__ rawS, unsigned int* __restrict__ hist)
{
    const int i = blockIdx.x * 256 + threadIdx.x;
    if (i < NBOX) {
        const unsigned int b = __float_as_uint(rawS[i]) >> 15;
        atomicAdd(&hist[b], 1u);
    }
}

__global__ __launch_bounds__(1024) void select_k(const unsigned int* __restrict__ hist,
                                                 int* __restrict__ params)
{
    __shared__ unsigned int ps[1024];
    const int t = threadIdx.x;
    unsigned int sum = 0;
    #pragma unroll 4
    for (int i = 0; i < 32; ++i) sum += hist[t * 32 + i];
    ps[t] = sum;
    __syncthreads();
    if (t == 0) {
        unsigned int run = 0;
        int bin = 0, need = 0;
        for (int c = 1023; c >= 0; --c) {
            if (run + ps[c] >= (unsigned)PRE_NMS) {
                unsigned int cum = run;
                for (int bb = c * 32 + 31; bb >= c * 32; --bb) {
                    const unsigned int h = hist[bb];
                    if (cum + h >= (unsigned)PRE_NMS) { bin = bb; need = PRE_NMS - (int)cum; break; }
                    cum += h;
                }
                break;
            }
            run += ps[c];
        }
        params[0] = bin;
        params[1] = need;
    }
}

__global__ void compact_k(const float* __restrict__ rawS, const float* __restrict__ nmsS,
                          const float* __restrict__ pY1, const float* __restrict__ pX1,
                          const float* __restrict__ pY2, const float* __restrict__ pX2,
                          const int* __restrict__ params, int* __restrict__ cnts,
                          float* __restrict__ cS,
                          float* __restrict__ cY1, float* __restrict__ cX1,
                          float* __restrict__ cY2, float* __restrict__ cX2)
{
    const int i = blockIdx.x * 256 + threadIdx.x;
    if (i >= NBOX) return;
    const int b = (int)(__float_as_uint(rawS[i]) >> 15);
    const int bin = params[0];
    const int need = params[1];
    int pos = -1;
    if (b > bin) {
        pos = atomicAdd(&cnts[0], 1);
    } else if (b == bin) {
        const int t2 = atomicAdd(&cnts[1], 1);
        if (t2 < need) pos = atomicAdd(&cnts[0], 1);
    }
    if (pos >= 0) {
        cS[pos]  = nmsS[i];
        cY1[pos] = pY1[i]; cX1[pos] = pX1[i];
        cY2[pos] = pY2[i]; cX2[pos] = pX2[i];
    }
}

// ============================================================
// sort_k: bitonic sort of 6000 candidates by nms score desc (exact 64-bit
// keys: ~mapped_score_bits << 32 | idx). Single block, LDS 8192 u64.
// ============================================================
__global__ __launch_bounds__(1024) void sort_k(
    const float* __restrict__ cS,
    const float* __restrict__ cY1, const float* __restrict__ cX1,
    const float* __restrict__ cY2, const float* __restrict__ cX2,
    float* __restrict__ sS,
    float* __restrict__ sY1, float* __restrict__ sX1,
    float* __restrict__ sY2, float* __restrict__ sX2,
    float* __restrict__ sAr)
{
    __shared__ unsigned long long keys[8192];
    const int t = threadIdx.x;
    for (int i = t; i < 8192; i += 1024) {
        unsigned long long k;
        if (i < PRE_NMS) {
            const unsigned b = __float_as_uint(cS[i]);
            const unsigned m = (b & 0x80000000u) ? ~b : (b | 0x80000000u);
            k = ((unsigned long long)(~m) << 32) | (unsigned)i;
        } else {
            k = ~0ULL;
        }
        keys[i] = k;
    }
    for (int kk = 2; kk <= 8192; kk <<= 1) {
        for (int j = kk >> 1; j > 0; j >>= 1) {
            __syncthreads();
            for (int t4 = t; t4 < 4096; t4 += 1024) {
                const int i  = ((t4 & ~(j - 1)) << 1) | (t4 & (j - 1));
                const int p2 = i | j;
                const bool up = ((i & kk) == 0);
                const unsigned long long a = keys[i], b = keys[p2];
                const bool sw = up ? (a > b) : (a < b);
                if (sw) { keys[i] = b; keys[p2] = a; }
            }
        }
    }
    __syncthreads();
    for (int i = t; i < NSORT; i += 1024) {
        if (i < PRE_NMS) {
            const int j = (int)(keys[i] & 0xFFFFFFFFu);
            const float y1 = cY1[j], x1 = cX1[j], y2 = cY2[j], x2 = cX2[j];
            sS[i] = cS[j];
            sY1[i] = y1; sX1[i] = x1; sY2[i] = y2; sX2[i] = x2;
            sAr[i] = (y2 - y1) * (x2 - x1);
        } else {
            sS[i] = -2.0e9f;
            sY1[i] = 0.f; sX1[i] = 0.f; sY2[i] = 0.f; sX2[i] = 0.f; sAr[i] = 0.f;
        }
    }
}

// ============================================================
// mask_k: suppression bitmask. Block (bi,bj) = rows bi*64.., cols bj*64..
// mask[r*94+bj] bit u = (iou(r, bj*64+u) > 0.7)
// ============================================================
__global__ __launch_bounds__(64) void mask_k(
    const float* __restrict__ sY1, const float* __restrict__ sX1,
    const float* __restrict__ sY2, const float* __restrict__ sX2,
    const float* __restrict__ sAr, unsigned long long* __restrict__ mask)
{
    __shared__ float ly1[64], lx1[64], ly2[64], lx2[64], lar[64];
    const int t = threadIdx.x;
    const int c = blockIdx.y * 64 + t;
    ly1[t] = sY1[c]; lx1[t] = sX1[c]; ly2[t] = sY2[c]; lx2[t] = sX2[c]; lar[t] = sAr[c];
    __syncthreads();
    const int r = blockIdx.x * 64 + t;
    const float ry1 = sY1[r], rx1 = sX1[r], ry2 = sY2[r], rx2 = sX2[r], rar = sAr[r];
    unsigned long long bits = 0ULL;
    #pragma unroll 8
    for (int u = 0; u < 64; ++u) {
        const float iy1 = fmaxf(ry1, ly1[u]);
        const float ix1 = fmaxf(rx1, lx1[u]);
        const float iy2 = fminf(ry2, ly2[u]);
        const float ix2 = fminf(rx2, lx2[u]);
        const float inter = fmaxf(iy2 - iy1, 0.f) * fmaxf(ix2 - ix1, 0.f);
        const float iou = inter / (lar[u] + rar - inter + 1e-8f);
        bits |= (iou > 0.7f) ? (1ULL << u) : 0ULL;
    }
    mask[(size_t)r * NWORDS + blockIdx.y] = bits;
}

// ============================================================
// scan_k: sequential greedy over sorted order, one wave, no barriers.
// remv bitmask lives in registers: lane l owns words l and 64+l.
// ============================================================
__global__ __launch_bounds__(64) void scan_k(
    const float* __restrict__ sS,
    const float* __restrict__ sY1, const float* __restrict__ sX1,
    const float* __restrict__ sY2, const float* __restrict__ sX2,
    const unsigned long long* __restrict__ mask, float* __restrict__ outP)
{
    const int l = threadIdx.x;
    unsigned long long r0 = 0ULL, r1 = 0ULL;
    int n = 0;
    bool done = false;
    for (int w = 0; w < NWORDS && !done; ++w) {
        unsigned long long cur = (w < 64) ? __shfl(r0, w, 64) : __shfl(r1, w - 64, 64);
        const int base = w << 6;
        const int lim = (PRE_NMS - base < 64) ? (PRE_NMS - base) : 64;
        for (int b = 0; b < lim; ++b) {
            if ((cur >> b) & 1ULL) continue;
            const int i = base + b;
            const float sc = sS[i];
            if (sc <= NEGV * 0.5f) { done = true; break; }
            if (l == 0) {
                outP[4 * n + 0] = sY1[i];
                outP[4 * n + 1] = sX1[i];
                outP[4 * n + 2] = sY2[i];
                outP[4 * n + 3] = sX2[i];
            }
            ++n;
            if (n >= POST_NMS) { done = true; break; }
            const unsigned long long* row = mask + (size_t)i * NWORDS;
            const unsigned long long m0 = row[l];
            const unsigned long long m1 = (l < NWORDS - 64) ? row[64 + l] : 0ULL;
            r0 |= m0; r1 |= m1;
            cur |= (w < 64) ? __shfl(m0, w, 64) : __shfl(m1, w - 64, 64);
        }
    }
    for (int idx = 4 * n + l; idx < 4 * POST_NMS; idx += 64) outP[idx] = 0.f;
}

// ============================================================
extern "C" void kernel_launch(void* const* d_in, const int* in_sizes, int n_in,
                              void* d_out, int out_size, void* d_ws, size_t ws_size,
                              hipStream_t stream)
{
    const float* X    = (const float*)d_in[1];
    const float* anch = (const float*)d_in[2];
    const float* W1   = (const float*)d_in[3];
    const float* b1   = (const float*)d_in[4];
    const float* Wc   = (const float*)d_in[5];
    const float* bc   = (const float*)d_in[6];
    const float* Wr   = (const float*)d_in[7];
    const float* br   = (const float*)d_in[8];

    float* out = (float*)d_out;
    float* ws  = (float*)d_ws;

    float* Y = ws + OY;
    unsigned short* Xh = (unsigned short*)(ws + OXH);
    unsigned short* Xl = (unsigned short*)(ws + OXL);
    unsigned short* Wh = (unsigned short*)(ws + OWH);
    unsigned short* Wl = (unsigned short*)(ws + OWL);
    float* rawS = ws + ORAW;
    float* nmsS = ws + ONMS;
    float* pY1  = ws + OPY1;
    float* pX1  = ws + OPX1;
    float* pY2  = ws + OPY2;
    float* pX2  = ws + OPX2;
    unsigned int* hist = (unsigned int*)(ws + OHIST);
    int* cnts   = (int*)(ws + OCNT);
    int* params = (int*)(ws + OPAR);
    float* cS   = ws + OCS;
    float* cY1  = ws + OCY1;
    float* cX1  = ws + OCX1;
    float* cY2  = ws + OCY2;
    float* cX2  = ws + OCX2;
    float* sS   = ws + OSS;
    float* sY1  = ws + OSY1;
    float* sX1  = ws + OSX1;
    float* sY2  = ws + OSY2;
    float* sX2  = ws + OSX2;
    float* sAr  = ws + OSAR;
    unsigned long long* mask = (unsigned long long*)(ws + OMASK);

    float* out_scores = out;
    float* out_deltas = out + NBOX;
    float* out_props  = out + (size_t)NBOX * 5;

    hipMemsetAsync(hist, 0, (NHBINS + 4) * sizeof(unsigned int), stream);
    hipMemsetAsync(Xh, 0, NPAD * sizeof(unsigned short), stream);
    hipMemsetAsync(Xl, 0, NPAD * sizeof(unsigned short), stream);

    split_x<<<8000, 256, 0, stream>>>(X, Xh, Xl);
    split_w<<<576, 256, 0, stream>>>(W1, Wh, Wl);

    conv_mfma<<<dim3(125, 4), 256, 0, stream>>>(Xh, Xl, Wh, Wl, b1, Y);

    heads_k<<<250, 64, 0, stream>>>(Y, Wc, bc, Wr, br, anch,
        out_scores, out_deltas, rawS, nmsS, pY1, pX1, pY2, pX2);

    hist_k<<<(NBOX + 255) / 256, 256, 0, stream>>>(rawS, hist);
    select_k<<<1, 1024, 0, stream>>>(hist, params);
    compact_k<<<(NBOX + 255) / 256, 256, 0, stream>>>(
        rawS, nmsS, pY1, pX1, pY2, pX2, params, cnts, cS, cY1, cX1, cY2, cX2);

    sort_k<<<1, 1024, 0, stream>>>(cS, cY1, cX1, cY2, cX2,
                                   sS, sY1, sX1, sY2, sX2, sAr);
    mask_k<<<dim3(NWORDS, NWORDS), 64, 0, stream>>>(sY1, sX1, sY2, sX2, sAr, mask);
    scan_k<<<1, 64, 0, stream>>>(sS, sY1, sX1, sY2, sX2, mask, out_props);
}

// Round 6
// 840.154 us; speedup vs baseline: 2.5257x; 1.1006x over previous
//
#include <hip/hip_runtime.h>
#include <math.h>

#define HF 100
#define WFD 160
#define CIN 512
#define CONV_C 512
#define NPIX (HF*WFD)           // 16000
#define NBOX (NPIX*9)           // 144000
#define PRE_NMS 6000
#define POST_NMS 300
#define NEGV (-1.0e9f)
#define IMG_H 1600.0f
#define IMG_W 2560.0f
#define NHBINS 32768
#define NWORDS 94               // ceil(6000/64)
#define NSORT 6016              // 94*64

// padded X: 102 rows x 162 cols x 512 ch
#define PR 102
#define PC 162
#define NPAD ((size_t)PR*PC*512)   // 8,460,288 elems

typedef __attribute__((ext_vector_type(8))) _Float16 half8;
typedef __attribute__((ext_vector_type(4))) float floatx4;

__device__ __forceinline__ unsigned short f2h_hi(float x) {
    _Float16 h = (_Float16)x;
    return __builtin_bit_cast(unsigned short, h);
}
__device__ __forceinline__ unsigned short f2h_lo(float x, unsigned short hbits) {
    _Float16 h = __builtin_bit_cast(_Float16, hbits);
    _Float16 l = (_Float16)((x - (float)h) * 2048.0f);   // scaled residual: stays normal
    return __builtin_bit_cast(unsigned short, l);
}

#define GLL16(g, l) __builtin_amdgcn_global_load_lds( \
    (const __attribute__((address_space(1))) void*)(g), \
    (__attribute__((address_space(3))) void*)(l), 16, 0, 0)

// ---- workspace layout (units: floats) ----
static const size_t OY    = 0;                              // 8,192,000 (dead after heads_k)
static const size_t OXH   = OY + (size_t)NPIX * CONV_C;     // fp16, NPAD elems
static const size_t OXL   = OXH + NPAD / 2;
static const size_t OWH   = OXL + NPAD / 2;                 // fp16 [9][n=512][k=512]
static const size_t OWL   = OWH + (size_t)9*512*512/2;
static const size_t ORAW  = OWL + (size_t)9*512*512/2;
static const size_t ONMS  = ORAW + NBOX;
static const size_t OPY1  = ONMS + NBOX;
static const size_t OPX1  = OPY1 + NBOX;
static const size_t OPY2  = OPX1 + NBOX;
static const size_t OPX2  = OPY2 + NBOX;
static const size_t OHIST = OPX2 + NBOX;                    // 32768 uints
static const size_t OCNT  = OHIST + NHBINS;                 // 4 ints: pos, tie, nValid, spare
static const size_t OPAR  = OCNT + 4;                       // 2 ints
static const size_t OCS   = OPAR + 2;                       // 6000
static const size_t OCY1  = OCS + PRE_NMS;
static const size_t OCX1  = OCY1 + PRE_NMS;
static const size_t OCY2  = OCX1 + PRE_NMS;
static const size_t OCX2  = OCY2 + PRE_NMS;
// sorted arrays + mask OVERLAY the Y region (Y dead after heads_k)
static const size_t OSY1  = OY;                             // 6016 each
static const size_t OSX1  = OSY1 + NSORT;
static const size_t OSY2  = OSX1 + NSORT;
static const size_t OSX2  = OSY2 + NSORT;
static const size_t OSAR  = OSX2 + NSORT;                   // ends 30,080
static const size_t OMASK = OY + 40000;                     // u64[6016*94] = 1,131,008 floats

// ============================================================
// split X (fp32) -> padded fp16 hi + scaled-lo
// ============================================================
__global__ __launch_bounds__(256) void split_x(
    const float* __restrict__ X,
    unsigned short* __restrict__ Xh, unsigned short* __restrict__ Xl)
{
    const int idx = blockIdx.x * 256 + threadIdx.x;
    const int p = idx >> 7;
    const int kq = (idx & 127) * 4;
    const float4 v = *(const float4*)(X + (size_t)p * 512 + kq);
    const int r = p / WFD, c = p % WFD;
    const size_t dst = ((size_t)(r + 1) * PC + (c + 1)) * 512 + kq;
    float vv[4] = { v.x, v.y, v.z, v.w };
    unsigned short h[4], lo[4];
    #pragma unroll
    for (int u = 0; u < 4; ++u) {
        h[u]  = f2h_hi(vv[u]);
        lo[u] = f2h_lo(vv[u], h[u]);
    }
    uint2 ph, pl;
    ph.x = (unsigned)h[0]  | ((unsigned)h[1]  << 16);
    ph.y = (unsigned)h[2]  | ((unsigned)h[3]  << 16);
    pl.x = (unsigned)lo[0] | ((unsigned)lo[1] << 16);
    pl.y = (unsigned)lo[2] | ((unsigned)lo[3] << 16);
    *(uint2*)(Xh + dst) = ph;
    *(uint2*)(Xl + dst) = pl;
}

// ============================================================
// split + transpose W1 [dydx][k][n] fp32 -> Wh/Wl [dydx][n][k] fp16
// ============================================================
__global__ __launch_bounds__(256) void split_w(
    const float* __restrict__ W1,
    unsigned short* __restrict__ Wh, unsigned short* __restrict__ Wl)
{
    __shared__ unsigned short Lh[64 * 64];
    __shared__ unsigned short Ll[64 * 64];
    const int t = threadIdx.x;
    const int dydx = blockIdx.x >> 6;
    const int rem  = blockIdx.x & 63;
    const int k0 = (rem >> 3) * 64, n0 = (rem & 7) * 64;

    #pragma unroll
    for (int i = 0; i < 4; ++i) {
        const int f = t + 256 * i;
        const int row = f >> 4;
        const int cp  = (f & 15) * 4;
        const float4 v = *(const float4*)(W1 + ((size_t)(dydx * 512 + k0 + row)) * 512 + n0 + cp);
        float vv[4] = { v.x, v.y, v.z, v.w };
        #pragma unroll
        for (int u = 0; u < 4; ++u) {
            const unsigned short h = f2h_hi(vv[u]);
            Lh[(cp + u) * 64 + row] = h;
            Ll[(cp + u) * 64 + row] = f2h_lo(vv[u], h);
        }
    }
    __syncthreads();
    const int n  = t >> 2;
    const int kp = (t & 3) * 16;
    const size_t gbase = ((size_t)(dydx * 512 + n0 + n)) * 512 + k0 + kp;
    *(uint4*)(Wh + gbase)     = *(const uint4*)(Lh + n * 64 + kp);
    *(uint4*)(Wh + gbase + 8) = *(const uint4*)(Lh + n * 64 + kp + 8);
    *(uint4*)(Wl + gbase)     = *(const uint4*)(Ll + n * 64 + kp);
    *(uint4*)(Wl + gbase + 8) = *(const uint4*)(Ll + n * 64 + kp + 8);
}

// ============================================================
// conv 3x3 512->512, split-fp16 3-pass MFMA (R4-verified math).
// R6: XCD-contiguity swizzle — blocks with same (bx&7) land on the same
// XCD (round-robin heuristic) and get a CONTIGUOUS pixel-tile strip, so
// the strip's X rows + this oc-group's W tile stay resident in that
// XCD's 4 MB L2. Pure index permutation; correctness-invariant.
// ============================================================
__global__ __launch_bounds__(256, 2) void conv_mfma(
    const unsigned short* __restrict__ Xh, const unsigned short* __restrict__ Xl,
    const unsigned short* __restrict__ Wh, const unsigned short* __restrict__ Wl,
    const float* __restrict__ b1, float* __restrict__ Y)
{
    __shared__ alignas(16) unsigned short Ah[128 * 32];
    __shared__ alignas(16) unsigned short Al[128 * 32];
    __shared__ alignas(16) unsigned short Bh[128 * 32];
    __shared__ alignas(16) unsigned short Bl[128 * 32];

    const int tid = threadIdx.x;
    const int w = tid >> 6, l = tid & 63;
    const int wy = w >> 1, wx = w & 1;

    // swizzle: q = bx&7 (XCD class for fixed by), s = bx>>3 (slot)
    // classes 0..4 get 16 tiles, 5..7 get 15; union covers 0..124 exactly
    const int bx = blockIdx.x;
    const int q = bx & 7, s5 = bx >> 3;
    const int tile = (q < 5) ? (q * 16 + s5) : (80 + (q - 5) * 15 + s5);
    const int pm0 = tile * 128, oc0 = blockIdx.y * 128;

    int aoff[2], boff[2], ldsOff[2];
    #pragma unroll
    for (int i = 0; i < 2; ++i) {
        const int m = w * 32 + i * 16 + (l >> 2);
        const int p = pm0 + m;
        const int r = p / WFD, c = p % WFD;
        aoff[i] = ((r + 1) * PC + (c + 1)) * 512 + (l & 3) * 8;
        boff[i] = (oc0 + m) * 512 + (l & 3) * 8;
        ldsOff[i] = (w * 32 + i * 16) * 32;
    }

    int afrag[4], bfrag[4];
    #pragma unroll
    for (int i = 0; i < 4; ++i) {
        afrag[i] = (wy * 64 + i * 16 + (l & 15)) * 32 + (l >> 4) * 8;
        bfrag[i] = (wx * 64 + i * 16 + (l & 15)) * 32 + (l >> 4) * 8;
    }

    floatx4 acc[4][4], accL[4][4];
    #pragma unroll
    for (int j = 0; j < 4; ++j) {
        const float bv = b1[oc0 + wx * 64 + j * 16 + (l & 15)];
        #pragma unroll
        for (int i = 0; i < 4; ++i) {
            acc[i][j][0] = bv; acc[i][j][1] = bv; acc[i][j][2] = bv; acc[i][j][3] = bv;
            accL[i][j][0] = 0.f; accL[i][j][1] = 0.f; accL[i][j][2] = 0.f; accL[i][j][3] = 0.f;
        }
    }

    for (int dydx = 0; dydx < 9; ++dydx) {
        const int dy = dydx / 3 - 1, dx = dydx % 3 - 1;
        const int dA = (dy * PC + dx) * 512;
        const int dB = dydx * (512 * 512);
        for (int k0 = 0; k0 < 512; k0 += 32) {
            __syncthreads();
            #pragma unroll
            for (int i = 0; i < 2; ++i) {
                GLL16(Xh + aoff[i] + dA + k0, Ah + ldsOff[i]);
                GLL16(Xl + aoff[i] + dA + k0, Al + ldsOff[i]);
                GLL16(Wh + boff[i] + dB + k0, Bh + ldsOff[i]);
                GLL16(Wl + boff[i] + dB + k0, Bl + ldsOff[i]);
            }
            __syncthreads();
            half8 fah[4], fal[4], fbh[4], fbl[4];
            #pragma unroll
            for (int i = 0; i < 4; ++i) {
                fah[i] = *(const half8*)(Ah + afrag[i]);
                fal[i] = *(const half8*)(Al + afrag[i]);
                fbh[i] = *(const half8*)(Bh + bfrag[i]);
                fbl[i] = *(const half8*)(Bl + bfrag[i]);
            }
            #pragma unroll
            for (int i = 0; i < 4; ++i)
                #pragma unroll
                for (int j = 0; j < 4; ++j) {
                    acc[i][j]  = __builtin_amdgcn_mfma_f32_16x16x32_f16(fah[i], fbh[j], acc[i][j], 0, 0, 0);
                    accL[i][j] = __builtin_amdgcn_mfma_f32_16x16x32_f16(fal[i], fbh[j], accL[i][j], 0, 0, 0);
                    accL[i][j] = __builtin_amdgcn_mfma_f32_16x16x32_f16(fah[i], fbl[j], accL[i][j], 0, 0, 0);
                }
        }
    }

    #pragma unroll
    for (int i = 0; i < 4; ++i) {
        const int row0 = pm0 + wy * 64 + i * 16 + (l >> 4) * 4;
        #pragma unroll
        for (int j = 0; j < 4; ++j) {
            const int col = oc0 + wx * 64 + j * 16 + (l & 15);
            #pragma unroll
            for (int r = 0; r < 4; ++r) {
                const float yv = acc[i][j][r] + accL[i][j][r] * 4.8828125e-4f;  // 1/2048
                Y[(size_t)(row0 + r) * 512 + col] = fmaxf(yv, 0.f);
            }
        }
    }
}

// ============================================================
// heads: LDS-staged (R2/R5-verified) + fused score histogram
// ============================================================
__global__ __launch_bounds__(64) void heads_k(
    const float* __restrict__ Y,
    const float* __restrict__ Wc, const float* __restrict__ bc,
    const float* __restrict__ Wr, const float* __restrict__ br,
    const float* __restrict__ anch,
    float* __restrict__ out_scores, float* __restrict__ out_deltas,
    float* __restrict__ rawS, float* __restrict__ nmsS,
    float* __restrict__ pY1, float* __restrict__ pX1,
    float* __restrict__ pY2, float* __restrict__ pX2,
    unsigned int* __restrict__ hist)
{
    __shared__ float Ys[64 * 17];
    const int t = threadIdx.x;
    const int p0 = blockIdx.x * 64;
    const int p = p0 + t;

    float ac[9], arr[36];
    #pragma unroll
    for (int a = 0; a < 9; ++a) ac[a] = bc[a];
    #pragma unroll
    for (int j = 0; j < 36; ++j) arr[j] = br[j];

    for (int k0 = 0; k0 < 512; k0 += 16) {
        __syncthreads();
        #pragma unroll
        for (int i = 0; i < 4; ++i) {
            const int f = t + 64 * i;
            const int row = f >> 2, part = f & 3;
            const float4 v = *(const float4*)(Y + (size_t)(p0 + row) * 512 + k0 + part * 4);
            float* d = Ys + row * 17 + part * 4;
            d[0] = v.x; d[1] = v.y; d[2] = v.z; d[3] = v.w;
        }
        __syncthreads();
        #pragma unroll 4
        for (int kk = 0; kk < 16; ++kk) {
            const float yv = Ys[t * 17 + kk];
            const int kg = k0 + kk;
            const float* wc = Wc + kg * 9;
            const float* wr = Wr + kg * 36;
            #pragma unroll
            for (int a = 0; a < 9; ++a) ac[a] = fmaf(yv, wc[a], ac[a]);
            #pragma unroll
            for (int j = 0; j < 36; ++j) arr[j] = fmaf(yv, wr[j], arr[j]);
        }
    }

    float m = ac[0];
    #pragma unroll
    for (int a = 1; a < 9; ++a) m = fmaxf(m, ac[a]);
    float s = 0.f, e[9];
    #pragma unroll
    for (int a = 0; a < 9; ++a) { e[a] = expf(ac[a] - m); s += e[a]; }
    #pragma unroll
    for (int a = 0; a < 9; ++a) e[a] = e[a] / s;

    #pragma unroll
    for (int a = 0; a < 9; ++a) out_scores[p * 9 + a] = e[a];
    #pragma unroll
    for (int a = 0; a < 9; ++a)
        *(float4*)(out_deltas + (size_t)p * 36 + 4 * a) =
            make_float4(arr[4*a], arr[4*a+1], arr[4*a+2], arr[4*a+3]);

    #pragma unroll
    for (int a = 0; a < 9; ++a) {
        const float4 an = *(const float4*)(anch + (size_t)p * 36 + 4 * a);
        const float cty = an.x + arr[4*a]   * an.z;
        const float ctx = an.y + arr[4*a+1] * an.w;
        const float szy = an.z * expf(arr[4*a+2]);
        const float szx = an.w * expf(arr[4*a+3]);
        float y1 = fmaxf(cty - 0.5f * szy, 0.f);
        float x1 = fmaxf(ctx - 0.5f * szx, 0.f);
        float y2 = fminf(cty + 0.5f * szy, IMG_H);
        float x2 = fminf(ctx + 0.5f * szx, IMG_W);
        const bool valid = ((y2 - y1) >= 16.f) && ((x2 - x1) >= 16.f);
        const int idx = p * 9 + a;
        rawS[idx] = e[a];
        nmsS[idx] = valid ? e[a] : NEGV;
        pY1[idx] = y1; pX1[idx] = x1; pY2[idx] = y2; pX2[idx] = x2;
        atomicAdd(&hist[__float_as_uint(e[a]) >> 15], 1u);
    }
}

// ============================================================
// select_k: parallel suffix-scan over histogram (replaces serial t==0 walk)
// ============================================================
__global__ __launch_bounds__(1024) void select_k(const unsigned int* __restrict__ hist,
                                                 int* __restrict__ params)
{
    __shared__ unsigned int ps[1024];
    const int t = threadIdx.x;
    unsigned int loc[32];
    unsigned int sum = 0;
    #pragma unroll 4
    for (int i = 0; i < 32; ++i) { loc[i] = hist[t * 32 + i]; sum += loc[i]; }
    ps[t] = sum;
    // suffix-inclusive sum: ps[t] = sum_{u>=t} chunk(u)
    for (int off = 1; off < 1024; off <<= 1) {
        __syncthreads();
        const unsigned int add = (t + off < 1024) ? ps[t + off] : 0u;
        __syncthreads();
        ps[t] += add;
    }
    __syncthreads();
    const unsigned int above = (t < 1023) ? ps[t + 1] : 0u;   // strictly-above-chunk sum
    if (above < (unsigned)PRE_NMS && ps[t] >= (unsigned)PRE_NMS) {
        unsigned int cum = above;
        for (int j = 31; j >= 0; --j) {
            const unsigned int h = loc[j];
            if (cum + h >= (unsigned)PRE_NMS) {
                params[0] = t * 32 + j;
                params[1] = PRE_NMS - (int)cum;
                break;
            }
            cum += h;
        }
    }
}

__global__ void compact_k(const float* __restrict__ rawS, const float* __restrict__ nmsS,
                          const float* __restrict__ pY1, const float* __restrict__ pX1,
                          const float* __restrict__ pY2, const float* __restrict__ pX2,
                          const int* __restrict__ params, int* __restrict__ cnts,
                          float* __restrict__ cS,
                          float* __restrict__ cY1, float* __restrict__ cX1,
                          float* __restrict__ cY2, float* __restrict__ cX2)
{
    const int i = blockIdx.x * 256 + threadIdx.x;
    if (i >= NBOX) return;
    const int b = (int)(__float_as_uint(rawS[i]) >> 15);
    const int bin = params[0];
    const int need = params[1];
    int pos = -1;
    if (b > bin) {
        pos = atomicAdd(&cnts[0], 1);
    } else if (b == bin) {
        const int t2 = atomicAdd(&cnts[1], 1);
        if (t2 < need) pos = atomicAdd(&cnts[0], 1);
    }
    if (pos >= 0) {
        const float sv = nmsS[i];
        cS[pos]  = sv;
        cY1[pos] = pY1[i]; cX1[pos] = pX1[i];
        cY2[pos] = pY2[i]; cX2[pos] = pX2[i];
        if (sv > NEGV * 0.5f) atomicAdd(&cnts[2], 1);   // valid-score count
    }
}

// ============================================================
// sort_k: bitonic sort of 6000 candidates by nms score desc (exact 64-bit
// keys). Single block, LDS 8192 u64. Gathers sorted SoA box arrays.
// ============================================================
__global__ __launch_bounds__(1024) void sort_k(
    const float* __restrict__ cS,
    const float* __restrict__ cY1, const float* __restrict__ cX1,
    const float* __restrict__ cY2, const float* __restrict__ cX2,
    float* __restrict__ sY1, float* __restrict__ sX1,
    float* __restrict__ sY2, float* __restrict__ sX2,
    float* __restrict__ sAr)
{
    __shared__ unsigned long long keys[8192];
    const int t = threadIdx.x;
    for (int i = t; i < 8192; i += 1024) {
        unsigned long long k;
        if (i < PRE_NMS) {
            const unsigned b = __float_as_uint(cS[i]);
            const unsigned m = (b & 0x80000000u) ? ~b : (b | 0x80000000u);
            k = ((unsigned long long)(~m) << 32) | (unsigned)i;
        } else {
            k = ~0ULL;
        }
        keys[i] = k;
    }
    for (int kk = 2; kk <= 8192; kk <<= 1) {
        for (int j = kk >> 1; j > 0; j >>= 1) {
            __syncthreads();
            for (int t4 = t; t4 < 4096; t4 += 1024) {
                const int i  = ((t4 & ~(j - 1)) << 1) | (t4 & (j - 1));
                const int p2 = i | j;
                const bool up = ((i & kk) == 0);
                const unsigned long long a = keys[i], b = keys[p2];
                const bool sw = up ? (a > b) : (a < b);
                if (sw) { keys[i] = b; keys[p2] = a; }
            }
        }
    }
    __syncthreads();
    for (int i = t; i < NSORT; i += 1024) {
        if (i < PRE_NMS) {
            const int j = (int)(keys[i] & 0xFFFFFFFFu);
            const float y1 = cY1[j], x1 = cX1[j], y2 = cY2[j], x2 = cX2[j];
            sY1[i] = y1; sX1[i] = x1; sY2[i] = y2; sX2[i] = x2;
            sAr[i] = (y2 - y1) * (x2 - x1);
        } else {
            sY1[i] = 0.f; sX1[i] = 0.f; sY2[i] = 0.f; sX2[i] = 0.f; sAr[i] = 0.f;
        }
    }
}

// ============================================================
// mask_k: suppression bitmask. mask[r*94+bj] bit u = iou(r, bj*64+u)>0.7
// ============================================================
__global__ __launch_bounds__(64) void mask_k(
    const float* __restrict__ sY1, const float* __restrict__ sX1,
    const float* __restrict__ sY2, const float* __restrict__ sX2,
    const float* __restrict__ sAr, unsigned long long* __restrict__ mask)
{
    __shared__ float ly1[64], lx1[64], ly2[64], lx2[64], lar[64];
    const int t = threadIdx.x;
    const int c = blockIdx.y * 64 + t;
    ly1[t] = sY1[c]; lx1[t] = sX1[c]; ly2[t] = sY2[c]; lx2[t] = sX2[c]; lar[t] = sAr[c];
    __syncthreads();
    const int r = blockIdx.x * 64 + t;
    const float ry1 = sY1[r], rx1 = sX1[r], ry2 = sY2[r], rx2 = sX2[r], rar = sAr[r];
    unsigned long long bits = 0ULL;
    #pragma unroll 8
    for (int u = 0; u < 64; ++u) {
        const float iy1 = fmaxf(ry1, ly1[u]);
        const float ix1 = fmaxf(rx1, lx1[u]);
        const float iy2 = fminf(ry2, ly2[u]);
        const float ix2 = fminf(rx2, lx2[u]);
        const float inter = fmaxf(iy2 - iy1, 0.f) * fmaxf(ix2 - ix1, 0.f);
        const float iou = inter / (lar[u] + rar - inter + 1e-8f);
        bits |= (iou > 0.7f) ? (1ULL << u) : 0ULL;
    }
    mask[(size_t)r * NWORDS + blockIdx.y] = bits;
}

// ============================================================
// scan2_k: chunked-LDS greedy scan. Per 64-candidate chunk: burst-load all
// 64 mask rows into LDS (latency amortized once per chunk), preload boxes,
// then walk picks entirely from LDS/registers. One wave, no global
// dependent-load chain per pick.
// ============================================================
__global__ __launch_bounds__(64) void scan2_k(
    const float* __restrict__ sY1, const float* __restrict__ sX1,
    const float* __restrict__ sY2, const float* __restrict__ sX2,
    const unsigned long long* __restrict__ mask, const int* __restrict__ cnts,
    float* __restrict__ outP)
{
    __shared__ alignas(16) unsigned long long rows[64][96];   // 96: pad
    const int l = threadIdx.x;
    const int nvRaw = cnts[2];
    const int nv = nvRaw < PRE_NMS ? nvRaw : PRE_NMS;
    unsigned long long r0 = 0ULL, r1 = 0ULL;   // lane l owns remv words l, 64+l
    int n = 0;
    for (int w = 0; w < NWORDS; ++w) {
        const int base = w << 6;
        if (base >= nv || n >= POST_NMS) break;
        // burst-load this chunk's 64 rows (47 lanes x 16B = 94 words/row)
        for (int r = 0; r < 64; ++r) {
            if (l < 47)
                GLL16(mask + (size_t)(base + r) * NWORDS + 2 * l, &rows[r][0]);
        }
        // preload this chunk's boxes (lane l holds candidate base+l)
        const int ci = base + l;
        const float v1 = sY1[ci], v2 = sX1[ci], v3 = sY2[ci], v4 = sX2[ci];
        __syncthreads();
        unsigned long long cw = (w < 64) ? __shfl(r0, w, 64) : __shfl(r1, w - 64, 64);
        const int lim = nv - base;
        if (lim < 64) cw |= (~0ULL << lim);
        while (cw != ~0ULL && n < POST_NMS) {
            const int b = (int)__builtin_ctzll(~cw);
            const float by1 = __shfl(v1, b, 64);
            const float bx1 = __shfl(v2, b, 64);
            const float by2 = __shfl(v3, b, 64);
            const float bx2 = __shfl(v4, b, 64);
            if (l == 0) {
                outP[4 * n + 0] = by1; outP[4 * n + 1] = bx1;
                outP[4 * n + 2] = by2; outP[4 * n + 3] = bx2;
            }
            ++n;
            cw |= (1ULL << b);
            if (n >= POST_NMS) break;
            r0 |= rows[b][l];
            if (l < NWORDS - 64) r1 |= rows[b][64 + l];
            cw |= rows[b][w];    // same-chunk suppression (broadcast read)
        }
        __syncthreads();
    }
    for (int idx = 4 * n + l; idx < 4 * POST_NMS; idx += 64) outP[idx] = 0.f;
}

// ============================================================
extern "C" void kernel_launch(void* const* d_in, const int* in_sizes, int n_in,
                              void* d_out, int out_size, void* d_ws, size_t ws_size,
                              hipStream_t stream)
{
    const float* X    = (const float*)d_in[1];
    const float* anch = (const float*)d_in[2];
    const float* W1   = (const float*)d_in[3];
    const float* b1   = (const float*)d_in[4];
    const float* Wc   = (const float*)d_in[5];
    const float* bc   = (const float*)d_in[6];
    const float* Wr   = (const float*)d_in[7];
    const float* br   = (const float*)d_in[8];

    float* out = (float*)d_out;
    float* ws  = (float*)d_ws;

    float* Y = ws + OY;
    unsigned short* Xh = (unsigned short*)(ws + OXH);
    unsigned short* Xl = (unsigned short*)(ws + OXL);
    unsigned short* Wh = (unsigned short*)(ws + OWH);
    unsigned short* Wl = (unsigned short*)(ws + OWL);
    float* rawS = ws + ORAW;
    float* nmsS = ws + ONMS;
    float* pY1  = ws + OPY1;
    float* pX1  = ws + OPX1;
    float* pY2  = ws + OPY2;
    float* pX2  = ws + OPX2;
    unsigned int* hist = (unsigned int*)(ws + OHIST);
    int* cnts   = (int*)(ws + OCNT);
    int* params = (int*)(ws + OPAR);
    float* cS   = ws + OCS;
    float* cY1  = ws + OCY1;
    float* cX1  = ws + OCX1;
    float* cY2  = ws + OCY2;
    float* cX2  = ws + OCX2;
    float* sY1  = ws + OSY1;
    float* sX1  = ws + OSX1;
    float* sY2  = ws + OSY2;
    float* sX2  = ws + OSX2;
    float* sAr  = ws + OSAR;
    unsigned long long* mask = (unsigned long long*)(ws + OMASK);

    float* out_scores = out;
    float* out_deltas = out + NBOX;
    float* out_props  = out + (size_t)NBOX * 5;

    // zero hist + cnts + params (contiguous) and padded X hi/lo (contiguous)
    hipMemsetAsync(hist, 0, (NHBINS + 8) * sizeof(unsigned int), stream);
    hipMemsetAsync(Xh, 0, 2 * NPAD * sizeof(unsigned short), stream);

    split_x<<<8000, 256, 0, stream>>>(X, Xh, Xl);
    split_w<<<576, 256, 0, stream>>>(W1, Wh, Wl);

    conv_mfma<<<dim3(125, 4), 256, 0, stream>>>(Xh, Xl, Wh, Wl, b1, Y);

    heads_k<<<250, 64, 0, stream>>>(Y, Wc, bc, Wr, br, anch,
        out_scores, out_deltas, rawS, nmsS, pY1, pX1, pY2, pX2, hist);

    select_k<<<1, 1024, 0, stream>>>(hist, params);
    compact_k<<<(NBOX + 255) / 256, 256, 0, stream>>>(
        rawS, nmsS, pY1, pX1, pY2, pX2, params, cnts, cS, cY1, cX1, cY2, cX2);

    sort_k<<<1, 1024, 0, stream>>>(cS, cY1, cX1, cY2, cX2,
                                   sY1, sX1, sY2, sX2, sAr);
    mask_k<<<dim3(NWORDS, NWORDS), 64, 0, stream>>>(sY1, sX1, sY2, sX2, sAr, mask);
    scan2_k<<<1, 64, 0, stream>>>(sY1, sX1, sY2, sX2, mask, cnts, out_props);
}

// Round 7
// 720.851 us; speedup vs baseline: 2.9437x; 1.1655x over previous
//
#include <hip/hip_runtime.h>
#include <math.h>

#define HF 100
#define WFD 160
#define CIN 512
#define CONV_C 512
#define NPIX (HF*WFD)           // 16000
#define NBOX (NPIX*9)           // 144000
#define PRE_NMS 6000
#define POST_NMS 300
#define NEGV (-1.0e9f)
#define IMG_H 1600.0f
#define IMG_W 2560.0f
#define NHBINS 32768
#define NWORDS 94               // ceil(6000/64)
#define NSORT 6016              // 94*64

// padded X: 102 rows x 162 cols x 512 ch
#define PR 102
#define PC 162
#define NPAD ((size_t)PR*PC*512)   // 8,460,288 ushorts per array

typedef __attribute__((ext_vector_type(8))) _Float16 half8;
typedef __attribute__((ext_vector_type(4))) float floatx4;

__device__ __forceinline__ unsigned short f2h_hi(float x) {
    _Float16 h = (_Float16)x;
    return __builtin_bit_cast(unsigned short, h);
}
__device__ __forceinline__ unsigned short f2h_lo(float x, unsigned short hbits) {
    _Float16 h = __builtin_bit_cast(_Float16, hbits);
    _Float16 l = (_Float16)((x - (float)h) * 2048.0f);   // scaled residual: stays normal
    return __builtin_bit_cast(unsigned short, l);
}

#define GLL16(g, l) __builtin_amdgcn_global_load_lds( \
    (const __attribute__((address_space(1))) void*)(g), \
    (__attribute__((address_space(3))) void*)(l), 16, 0, 0)

// ---- workspace layout (units: floats) ----
// [0, 8.192M): Yh+Yl fp16 (each NPIX*512 ushorts) — dead after heads;
//              NOT overlaid (mask/sorted moved to X regions).
static const size_t OYREG = 0;
static const size_t OXH   = OYREG + (size_t)NPIX * CONV_C;  // Xh ushorts; dead after conv
static const size_t OXL   = OXH + NPAD / 2;                 // Xl ushorts; dead after conv
static const size_t OWH   = OXL + NPAD / 2;                 // fp16 [9][n=512][k=512]
static const size_t OWL   = OWH + (size_t)9*512*512/2;
static const size_t ORAW  = OWL + (size_t)9*512*512/2;
static const size_t ONMS  = ORAW + NBOX;
static const size_t OPY1  = ONMS + NBOX;
static const size_t OPX1  = OPY1 + NBOX;
static const size_t OPY2  = OPX1 + NBOX;
static const size_t OPX2  = OPY2 + NBOX;
static const size_t OHIST = OPX2 + NBOX;                    // 32768 uints
static const size_t OCNT  = OHIST + NHBINS;                 // 4 ints
static const size_t OPAR  = OCNT + 4;                       // 2 ints
static const size_t OCS   = OPAR + 2;                       // 6000
static const size_t OCY1  = OCS + PRE_NMS;
static const size_t OCX1  = OCY1 + PRE_NMS;
static const size_t OCY2  = OCX1 + PRE_NMS;
static const size_t OCX2  = OCY2 + PRE_NMS;
static const size_t OW2H  = OCX2 + PRE_NMS;                 // 48*512 ushorts = 12288 floats
static const size_t OW2L  = OW2H + 12288;
// overlays (written after conv_mfma is done):
static const size_t OMASK = OXH;                            // u64[6016*94] = 1.131M floats <= 2.115M
static const size_t OSY1  = OXL;                            // 6016 each, 5 arrays
static const size_t OSX1  = OSY1 + NSORT;
static const size_t OSY2  = OSX1 + NSORT;
static const size_t OSX2  = OSY2 + NSORT;
static const size_t OSAR  = OSX2 + NSORT;

// ============================================================
// split X (fp32) -> padded fp16 hi + scaled-lo
// ============================================================
__global__ __launch_bounds__(256) void split_x(
    const float* __restrict__ X,
    unsigned short* __restrict__ Xh, unsigned short* __restrict__ Xl)
{
    const int idx = blockIdx.x * 256 + threadIdx.x;
    const int p = idx >> 7;
    const int kq = (idx & 127) * 4;
    const float4 v = *(const float4*)(X + (size_t)p * 512 + kq);
    const int r = p / WFD, c = p % WFD;
    const size_t dst = ((size_t)(r + 1) * PC + (c + 1)) * 512 + kq;
    float vv[4] = { v.x, v.y, v.z, v.w };
    unsigned short h[4], lo[4];
    #pragma unroll
    for (int u = 0; u < 4; ++u) {
        h[u]  = f2h_hi(vv[u]);
        lo[u] = f2h_lo(vv[u], h[u]);
    }
    uint2 ph, pl;
    ph.x = (unsigned)h[0]  | ((unsigned)h[1]  << 16);
    ph.y = (unsigned)h[2]  | ((unsigned)h[3]  << 16);
    pl.x = (unsigned)lo[0] | ((unsigned)lo[1] << 16);
    pl.y = (unsigned)lo[2] | ((unsigned)lo[3] << 16);
    *(uint2*)(Xh + dst) = ph;
    *(uint2*)(Xl + dst) = pl;
}

// ============================================================
// split + transpose W1 [dydx][k][n] fp32 -> Wh/Wl [dydx][n][k] fp16
// ============================================================
__global__ __launch_bounds__(256) void split_w(
    const float* __restrict__ W1,
    unsigned short* __restrict__ Wh, unsigned short* __restrict__ Wl)
{
    __shared__ unsigned short Lh[64 * 64];
    __shared__ unsigned short Ll[64 * 64];
    const int t = threadIdx.x;
    const int dydx = blockIdx.x >> 6;
    const int rem  = blockIdx.x & 63;
    const int k0 = (rem >> 3) * 64, n0 = (rem & 7) * 64;

    #pragma unroll
    for (int i = 0; i < 4; ++i) {
        const int f = t + 256 * i;
        const int row = f >> 4;
        const int cp  = (f & 15) * 4;
        const float4 v = *(const float4*)(W1 + ((size_t)(dydx * 512 + k0 + row)) * 512 + n0 + cp);
        float vv[4] = { v.x, v.y, v.z, v.w };
        #pragma unroll
        for (int u = 0; u < 4; ++u) {
            const unsigned short h = f2h_hi(vv[u]);
            Lh[(cp + u) * 64 + row] = h;
            Ll[(cp + u) * 64 + row] = f2h_lo(vv[u], h);
        }
    }
    __syncthreads();
    const int n  = t >> 2;
    const int kp = (t & 3) * 16;
    const size_t gbase = ((size_t)(dydx * 512 + n0 + n)) * 512 + k0 + kp;
    *(uint4*)(Wh + gbase)     = *(const uint4*)(Lh + n * 64 + kp);
    *(uint4*)(Wh + gbase + 8) = *(const uint4*)(Lh + n * 64 + kp + 8);
    *(uint4*)(Wl + gbase)     = *(const uint4*)(Ll + n * 64 + kp);
    *(uint4*)(Wl + gbase + 8) = *(const uint4*)(Ll + n * 64 + kp + 8);
}

// ============================================================
// split head weights: Wc[512][9] + Wr[512][36] -> [n=48][k=512] fp16 hi/lo
// (n 0..8 = score cols, 9..44 = delta cols, 45..47 = zero pad)
// ============================================================
__global__ __launch_bounds__(256) void split_w2(
    const float* __restrict__ Wc, const float* __restrict__ Wr,
    unsigned short* __restrict__ W2h, unsigned short* __restrict__ W2l)
{
    const int i = blockIdx.x * 256 + threadIdx.x;   // 0..24575
    if (i >= 48 * 512) return;
    const int n = i >> 9, k = i & 511;
    float v = 0.f;
    if (n < 9) v = Wc[k * 9 + n];
    else if (n < 45) v = Wr[k * 36 + (n - 9)];
    const unsigned short h = f2h_hi(v);
    W2h[i] = h;
    W2l[i] = f2h_lo(v, h);
}

// ============================================================
// conv 3x3 512->512, split-fp16 3-pass MFMA (R4-verified math).
// Epilogue now writes Yh/Yl fp16 (hi + scaled-lo) for the heads GEMM.
// ============================================================
__global__ __launch_bounds__(256, 2) void conv_mfma(
    const unsigned short* __restrict__ Xh, const unsigned short* __restrict__ Xl,
    const unsigned short* __restrict__ Wh, const unsigned short* __restrict__ Wl,
    const float* __restrict__ b1,
    unsigned short* __restrict__ Yh, unsigned short* __restrict__ Yl)
{
    __shared__ alignas(16) unsigned short Ah[128 * 32];
    __shared__ alignas(16) unsigned short Al[128 * 32];
    __shared__ alignas(16) unsigned short Bh[128 * 32];
    __shared__ alignas(16) unsigned short Bl[128 * 32];

    const int tid = threadIdx.x;
    const int w = tid >> 6, l = tid & 63;
    const int wy = w >> 1, wx = w & 1;

    const int bx = blockIdx.x;
    const int q = bx & 7, s5 = bx >> 3;
    const int tile = (q < 5) ? (q * 16 + s5) : (80 + (q - 5) * 15 + s5);
    const int pm0 = tile * 128, oc0 = blockIdx.y * 128;

    int aoff[2], boff[2], ldsOff[2];
    #pragma unroll
    for (int i = 0; i < 2; ++i) {
        const int m = w * 32 + i * 16 + (l >> 2);
        const int p = pm0 + m;
        const int r = p / WFD, c = p % WFD;
        aoff[i] = ((r + 1) * PC + (c + 1)) * 512 + (l & 3) * 8;
        boff[i] = (oc0 + m) * 512 + (l & 3) * 8;
        ldsOff[i] = (w * 32 + i * 16) * 32;
    }

    int afrag[4], bfrag[4];
    #pragma unroll
    for (int i = 0; i < 4; ++i) {
        afrag[i] = (wy * 64 + i * 16 + (l & 15)) * 32 + (l >> 4) * 8;
        bfrag[i] = (wx * 64 + i * 16 + (l & 15)) * 32 + (l >> 4) * 8;
    }

    floatx4 acc[4][4], accL[4][4];
    #pragma unroll
    for (int j = 0; j < 4; ++j) {
        const float bv = b1[oc0 + wx * 64 + j * 16 + (l & 15)];
        #pragma unroll
        for (int i = 0; i < 4; ++i) {
            acc[i][j][0] = bv; acc[i][j][1] = bv; acc[i][j][2] = bv; acc[i][j][3] = bv;
            accL[i][j][0] = 0.f; accL[i][j][1] = 0.f; accL[i][j][2] = 0.f; accL[i][j][3] = 0.f;
        }
    }

    for (int dydx = 0; dydx < 9; ++dydx) {
        const int dy = dydx / 3 - 1, dx = dydx % 3 - 1;
        const int dA = (dy * PC + dx) * 512;
        const int dB = dydx * (512 * 512);
        for (int k0 = 0; k0 < 512; k0 += 32) {
            __syncthreads();
            #pragma unroll
            for (int i = 0; i < 2; ++i) {
                GLL16(Xh + aoff[i] + dA + k0, Ah + ldsOff[i]);
                GLL16(Xl + aoff[i] + dA + k0, Al + ldsOff[i]);
                GLL16(Wh + boff[i] + dB + k0, Bh + ldsOff[i]);
                GLL16(Wl + boff[i] + dB + k0, Bl + ldsOff[i]);
            }
            __syncthreads();
            half8 fah[4], fal[4], fbh[4], fbl[4];
            #pragma unroll
            for (int i = 0; i < 4; ++i) {
                fah[i] = *(const half8*)(Ah + afrag[i]);
                fal[i] = *(const half8*)(Al + afrag[i]);
                fbh[i] = *(const half8*)(Bh + bfrag[i]);
                fbl[i] = *(const half8*)(Bl + bfrag[i]);
            }
            #pragma unroll
            for (int i = 0; i < 4; ++i)
                #pragma unroll
                for (int j = 0; j < 4; ++j) {
                    acc[i][j]  = __builtin_amdgcn_mfma_f32_16x16x32_f16(fah[i], fbh[j], acc[i][j], 0, 0, 0);
                    accL[i][j] = __builtin_amdgcn_mfma_f32_16x16x32_f16(fal[i], fbh[j], accL[i][j], 0, 0, 0);
                    accL[i][j] = __builtin_amdgcn_mfma_f32_16x16x32_f16(fah[i], fbl[j], accL[i][j], 0, 0, 0);
                }
        }
    }

    // epilogue: ReLU + fp16 hi/lo split + store
    #pragma unroll
    for (int i = 0; i < 4; ++i) {
        const int row0 = pm0 + wy * 64 + i * 16 + (l >> 4) * 4;
        #pragma unroll
        for (int j = 0; j < 4; ++j) {
            const int col = oc0 + wx * 64 + j * 16 + (l & 15);
            #pragma unroll
            for (int r = 0; r < 4; ++r) {
                const float yv = fmaxf(acc[i][j][r] + accL[i][j][r] * 4.8828125e-4f, 0.f);
                const unsigned short h = f2h_hi(yv);
                const size_t o = (size_t)(row0 + r) * 512 + col;
                Yh[o] = h;
                Yl[o] = f2h_lo(yv, h);
            }
        }
    }
}

// ============================================================
// heads as skinny split-fp16 MFMA GEMM: Y[16000x512] @ W[512x48].
// 125 blocks x 256 thr; block = 128 pixels. Logits -> LDS -> per-pixel
// epilogue (bias + softmax + decode + hist).
// ============================================================
__global__ __launch_bounds__(256) void heads_mfma(
    const unsigned short* __restrict__ Yh, const unsigned short* __restrict__ Yl,
    const unsigned short* __restrict__ W2h, const unsigned short* __restrict__ W2l,
    const float* __restrict__ bc, const float* __restrict__ br,
    const float* __restrict__ anch,
    float* __restrict__ out_scores, float* __restrict__ out_deltas,
    float* __restrict__ rawS, float* __restrict__ nmsS,
    float* __restrict__ pY1, float* __restrict__ pX1,
    float* __restrict__ pY2, float* __restrict__ pX2,
    unsigned int* __restrict__ hist)
{
    __shared__ alignas(16) unsigned short Ah[128 * 32];
    __shared__ alignas(16) unsigned short Al[128 * 32];
    __shared__ alignas(16) unsigned short Bh[48 * 32];
    __shared__ alignas(16) unsigned short Bl[48 * 32];
    __shared__ float Lg[128 * 48];

    const int tid = threadIdx.x;
    const int w = tid >> 6, l = tid & 63;
    const int pm0 = blockIdx.x * 128;

    // A staging offsets: wave w covers pixel rows [w*32, w*32+32), 2 issues
    int aoff[2], ldsOff[2];
    #pragma unroll
    for (int i = 0; i < 2; ++i) {
        const int m = w * 32 + i * 16 + (l >> 2);
        aoff[i] = (pm0 + m) * 512 + (l & 3) * 8;
        ldsOff[i] = (w * 32 + i * 16) * 32;
    }
    // B staging: waves 0..2 each cover 16 weight rows
    const int bglb = (w * 16 + (l >> 2)) * 512 + (l & 3) * 8;  // valid for w<3
    const int blds = w * 16 * 32;

    int afrag[2], bfrag[3];
    #pragma unroll
    for (int i = 0; i < 2; ++i)
        afrag[i] = (w * 32 + i * 16 + (l & 15)) * 32 + (l >> 4) * 8;
    #pragma unroll
    for (int j = 0; j < 3; ++j)
        bfrag[j] = (j * 16 + (l & 15)) * 32 + (l >> 4) * 8;

    floatx4 acc[2][3], accL[2][3];
    #pragma unroll
    for (int i = 0; i < 2; ++i)
        #pragma unroll
        for (int j = 0; j < 3; ++j) {
            acc[i][j][0] = 0.f; acc[i][j][1] = 0.f; acc[i][j][2] = 0.f; acc[i][j][3] = 0.f;
            accL[i][j] = acc[i][j];
        }

    for (int k0 = 0; k0 < 512; k0 += 32) {
        __syncthreads();
        #pragma unroll
        for (int i = 0; i < 2; ++i) {
            GLL16(Yh + aoff[i] + k0, Ah + ldsOff[i]);
            GLL16(Yl + aoff[i] + k0, Al + ldsOff[i]);
        }
        if (w < 3) {
            GLL16(W2h + bglb + k0, Bh + blds);
            GLL16(W2l + bglb + k0, Bl + blds);
        }
        __syncthreads();
        half8 fah[2], fal[2], fbh[3], fbl[3];
        #pragma unroll
        for (int i = 0; i < 2; ++i) {
            fah[i] = *(const half8*)(Ah + afrag[i]);
            fal[i] = *(const half8*)(Al + afrag[i]);
        }
        #pragma unroll
        for (int j = 0; j < 3; ++j) {
            fbh[j] = *(const half8*)(Bh + bfrag[j]);
            fbl[j] = *(const half8*)(Bl + bfrag[j]);
        }
        #pragma unroll
        for (int i = 0; i < 2; ++i)
            #pragma unroll
            for (int j = 0; j < 3; ++j) {
                acc[i][j]  = __builtin_amdgcn_mfma_f32_16x16x32_f16(fah[i], fbh[j], acc[i][j], 0, 0, 0);
                accL[i][j] = __builtin_amdgcn_mfma_f32_16x16x32_f16(fal[i], fbh[j], accL[i][j], 0, 0, 0);
                accL[i][j] = __builtin_amdgcn_mfma_f32_16x16x32_f16(fah[i], fbl[j], accL[i][j], 0, 0, 0);
            }
    }

    // logits -> LDS. C/D: col=lane&15, row=(lane>>4)*4+reg
    __syncthreads();
    #pragma unroll
    for (int i = 0; i < 2; ++i) {
        const int prow0 = w * 32 + i * 16 + (l >> 4) * 4;
        #pragma unroll
        for (int j = 0; j < 3; ++j) {
            const int col = j * 16 + (l & 15);
            #pragma unroll
            for (int r = 0; r < 4; ++r)
                Lg[(prow0 + r) * 48 + col] = acc[i][j][r] + accL[i][j][r] * 4.8828125e-4f;
        }
    }
    __syncthreads();

    if (tid < 128) {
        const int p = pm0 + tid;
        float ac[9], arr[36];
        #pragma unroll
        for (int a = 0; a < 9; ++a) ac[a] = Lg[tid * 48 + a] + bc[a];
        #pragma unroll
        for (int j = 0; j < 36; ++j) arr[j] = Lg[tid * 48 + 9 + j] + br[j];

        float m = ac[0];
        #pragma unroll
        for (int a = 1; a < 9; ++a) m = fmaxf(m, ac[a]);
        float s = 0.f, e[9];
        #pragma unroll
        for (int a = 0; a < 9; ++a) { e[a] = expf(ac[a] - m); s += e[a]; }
        #pragma unroll
        for (int a = 0; a < 9; ++a) e[a] = e[a] / s;

        #pragma unroll
        for (int a = 0; a < 9; ++a) out_scores[p * 9 + a] = e[a];
        #pragma unroll
        for (int a = 0; a < 9; ++a)
            *(float4*)(out_deltas + (size_t)p * 36 + 4 * a) =
                make_float4(arr[4*a], arr[4*a+1], arr[4*a+2], arr[4*a+3]);

        #pragma unroll
        for (int a = 0; a < 9; ++a) {
            const float4 an = *(const float4*)(anch + (size_t)p * 36 + 4 * a);
            const float cty = an.x + arr[4*a]   * an.z;
            const float ctx = an.y + arr[4*a+1] * an.w;
            const float szy = an.z * expf(arr[4*a+2]);
            const float szx = an.w * expf(arr[4*a+3]);
            float y1 = fmaxf(cty - 0.5f * szy, 0.f);
            float x1 = fmaxf(ctx - 0.5f * szx, 0.f);
            float y2 = fminf(cty + 0.5f * szy, IMG_H);
            float x2 = fminf(ctx + 0.5f * szx, IMG_W);
            const bool valid = ((y2 - y1) >= 16.f) && ((x2 - x1) >= 16.f);
            const int idx = p * 9 + a;
            rawS[idx] = e[a];
            nmsS[idx] = valid ? e[a] : NEGV;
            pY1[idx] = y1; pX1[idx] = x1; pY2[idx] = y2; pX2[idx] = x2;
            atomicAdd(&hist[__float_as_uint(e[a]) >> 15], 1u);
        }
    }
}

// ============================================================
// select_k: parallel suffix-scan over histogram
// ============================================================
__global__ __launch_bounds__(1024) void select_k(const unsigned int* __restrict__ hist,
                                                 int* __restrict__ params)
{
    __shared__ unsigned int ps[1024];
    const int t = threadIdx.x;
    unsigned int loc[32];
    unsigned int sum = 0;
    #pragma unroll 4
    for (int i = 0; i < 32; ++i) { loc[i] = hist[t * 32 + i]; sum += loc[i]; }
    ps[t] = sum;
    for (int off = 1; off < 1024; off <<= 1) {
        __syncthreads();
        const unsigned int add = (t + off < 1024) ? ps[t + off] : 0u;
        __syncthreads();
        ps[t] += add;
    }
    __syncthreads();
    const unsigned int above = (t < 1023) ? ps[t + 1] : 0u;
    if (above < (unsigned)PRE_NMS && ps[t] >= (unsigned)PRE_NMS) {
        unsigned int cum = above;
        for (int j = 31; j >= 0; --j) {
            const unsigned int h = loc[j];
            if (cum + h >= (unsigned)PRE_NMS) {
                params[0] = t * 32 + j;
                params[1] = PRE_NMS - (int)cum;
                break;
            }
            cum += h;
        }
    }
}

__global__ void compact_k(const float* __restrict__ rawS, const float* __restrict__ nmsS,
                          const float* __restrict__ pY1, const float* __restrict__ pX1,
                          const float* __restrict__ pY2, const float* __restrict__ pX2,
                          const int* __restrict__ params, int* __restrict__ cnts,
                          float* __restrict__ cS,
                          float* __restrict__ cY1, float* __restrict__ cX1,
                          float* __restrict__ cY2, float* __restrict__ cX2)
{
    const int i = blockIdx.x * 256 + threadIdx.x;
    if (i >= NBOX) return;
    const int b = (int)(__float_as_uint(rawS[i]) >> 15);
    const int bin = params[0];
    const int need = params[1];
    int pos = -1;
    if (b > bin) {
        pos = atomicAdd(&cnts[0], 1);
    } else if (b == bin) {
        const int t2 = atomicAdd(&cnts[1], 1);
        if (t2 < need) pos = atomicAdd(&cnts[0], 1);
    }
    if (pos >= 0) {
        const float sv = nmsS[i];
        cS[pos]  = sv;
        cY1[pos] = pY1[i]; cX1[pos] = pX1[i];
        cY2[pos] = pY2[i]; cX2[pos] = pX2[i];
        if (sv > NEGV * 0.5f) atomicAdd(&cnts[2], 1);
    }
}

// ============================================================
// sort_k: bitonic sort by score desc (exact 64-bit keys), gathers SoA boxes
// ============================================================
__global__ __launch_bounds__(1024) void sort_k(
    const float* __restrict__ cS,
    const float* __restrict__ cY1, const float* __restrict__ cX1,
    const float* __restrict__ cY2, const float* __restrict__ cX2,
    float* __restrict__ sY1, float* __restrict__ sX1,
    float* __restrict__ sY2, float* __restrict__ sX2,
    float* __restrict__ sAr)
{
    __shared__ unsigned long long keys[8192];
    const int t = threadIdx.x;
    for (int i = t; i < 8192; i += 1024) {
        unsigned long long k;
        if (i < PRE_NMS) {
            const unsigned b = __float_as_uint(cS[i]);
            const unsigned m = (b & 0x80000000u) ? ~b : (b | 0x80000000u);
            k = ((unsigned long long)(~m) << 32) | (unsigned)i;
        } else {
            k = ~0ULL;
        }
        keys[i] = k;
    }
    for (int kk = 2; kk <= 8192; kk <<= 1) {
        for (int j = kk >> 1; j > 0; j >>= 1) {
            __syncthreads();
            for (int t4 = t; t4 < 4096; t4 += 1024) {
                const int i  = ((t4 & ~(j - 1)) << 1) | (t4 & (j - 1));
                const int p2 = i | j;
                const bool up = ((i & kk) == 0);
                const unsigned long long a = keys[i], b = keys[p2];
                const bool sw = up ? (a > b) : (a < b);
                if (sw) { keys[i] = b; keys[p2] = a; }
            }
        }
    }
    __syncthreads();
    for (int i = t; i < NSORT; i += 1024) {
        if (i < PRE_NMS) {
            const int j = (int)(keys[i] & 0xFFFFFFFFu);
            const float y1 = cY1[j], x1 = cX1[j], y2 = cY2[j], x2 = cX2[j];
            sY1[i] = y1; sX1[i] = x1; sY2[i] = y2; sX2[i] = x2;
            sAr[i] = (y2 - y1) * (x2 - x1);
        } else {
            sY1[i] = 0.f; sX1[i] = 0.f; sY2[i] = 0.f; sX2[i] = 0.f; sAr[i] = 0.f;
        }
    }
}

// ============================================================
// mask_k: suppression bitmask. mask[r*94+bj] bit u = iou(r, bj*64+u)>0.7
// ============================================================
__global__ __launch_bounds__(64) void mask_k(
    const float* __restrict__ sY1, const float* __restrict__ sX1,
    const float* __restrict__ sY2, const float* __restrict__ sX2,
    const float* __restrict__ sAr, unsigned long long* __restrict__ mask)
{
    __shared__ float ly1[64], lx1[64], ly2[64], lx2[64], lar[64];
    const int t = threadIdx.x;
    const int c = blockIdx.y * 64 + t;
    ly1[t] = sY1[c]; lx1[t] = sX1[c]; ly2[t] = sY2[c]; lx2[t] = sX2[c]; lar[t] = sAr[c];
    __syncthreads();
    const int r = blockIdx.x * 64 + t;
    const float ry1 = sY1[r], rx1 = sX1[r], ry2 = sY2[r], rx2 = sX2[r], rar = sAr[r];
    unsigned long long bits = 0ULL;
    #pragma unroll 8
    for (int u = 0; u < 64; ++u) {
        const float iy1 = fmaxf(ry1, ly1[u]);
        const float ix1 = fmaxf(rx1, lx1[u]);
        const float iy2 = fminf(ry2, ly2[u]);
        const float ix2 = fminf(rx2, lx2[u]);
        const float inter = fmaxf(iy2 - iy1, 0.f) * fmaxf(ix2 - ix1, 0.f);
        const float iou = inter / (lar[u] + rar - inter + 1e-8f);
        bits |= (iou > 0.7f) ? (1ULL << u) : 0ULL;
    }
    mask[(size_t)r * NWORDS + blockIdx.y] = bits;
}

// ============================================================
// scan2_k: chunked-LDS greedy scan, one wave, no barrier-per-pick
// ============================================================
__global__ __launch_bounds__(64) void scan2_k(
    const float* __restrict__ sY1, const float* __restrict__ sX1,
    const float* __restrict__ sY2, const float* __restrict__ sX2,
    const unsigned long long* __restrict__ mask, const int* __restrict__ cnts,
    float* __restrict__ outP)
{
    __shared__ alignas(16) unsigned long long rows[64][96];
    const int l = threadIdx.x;
    const int nvRaw = cnts[2];
    const int nv = nvRaw < PRE_NMS ? nvRaw : PRE_NMS;
    unsigned long long r0 = 0ULL, r1 = 0ULL;
    int n = 0;
    for (int w = 0; w < NWORDS; ++w) {
        const int base = w << 6;
        if (base >= nv || n >= POST_NMS) break;
        for (int r = 0; r < 64; ++r) {
            if (l < 47)
                GLL16(mask + (size_t)(base + r) * NWORDS + 2 * l, &rows[r][0]);
        }
        const int ci = base + l;
        const float v1 = sY1[ci], v2 = sX1[ci], v3 = sY2[ci], v4 = sX2[ci];
        __syncthreads();
        unsigned long long cw = (w < 64) ? __shfl(r0, w, 64) : __shfl(r1, w - 64, 64);
        const int lim = nv - base;
        if (lim < 64) cw |= (~0ULL << lim);
        while (cw != ~0ULL && n < POST_NMS) {
            const int b = (int)__builtin_ctzll(~cw);
            const float by1 = __shfl(v1, b, 64);
            const float bx1 = __shfl(v2, b, 64);
            const float by2 = __shfl(v3, b, 64);
            const float bx2 = __shfl(v4, b, 64);
            if (l == 0) {
                outP[4 * n + 0] = by1; outP[4 * n + 1] = bx1;
                outP[4 * n + 2] = by2; outP[4 * n + 3] = bx2;
            }
            ++n;
            cw |= (1ULL << b);
            if (n >= POST_NMS) break;
            r0 |= rows[b][l];
            if (l < NWORDS - 64) r1 |= rows[b][64 + l];
            cw |= rows[b][w];
        }
        __syncthreads();
    }
    for (int idx = 4 * n + l; idx < 4 * POST_NMS; idx += 64) outP[idx] = 0.f;
}

// ============================================================
extern "C" void kernel_launch(void* const* d_in, const int* in_sizes, int n_in,
                              void* d_out, int out_size, void* d_ws, size_t ws_size,
                              hipStream_t stream)
{
    const float* X    = (const float*)d_in[1];
    const float* anch = (const float*)d_in[2];
    const float* W1   = (const float*)d_in[3];
    const float* b1   = (const float*)d_in[4];
    const float* Wc   = (const float*)d_in[5];
    const float* bc   = (const float*)d_in[6];
    const float* Wr   = (const float*)d_in[7];
    const float* br   = (const float*)d_in[8];

    float* out = (float*)d_out;
    float* ws  = (float*)d_ws;

    unsigned short* Yh = (unsigned short*)(ws + OYREG);
    unsigned short* Yl = Yh + (size_t)NPIX * CONV_C;
    unsigned short* Xh = (unsigned short*)(ws + OXH);
    unsigned short* Xl = (unsigned short*)(ws + OXL);
    unsigned short* Wh = (unsigned short*)(ws + OWH);
    unsigned short* Wl = (unsigned short*)(ws + OWL);
    float* rawS = ws + ORAW;
    float* nmsS = ws + ONMS;
    float* pY1  = ws + OPY1;
    float* pX1  = ws + OPX1;
    float* pY2  = ws + OPY2;
    float* pX2  = ws + OPX2;
    unsigned int* hist = (unsigned int*)(ws + OHIST);
    int* cnts   = (int*)(ws + OCNT);
    int* params = (int*)(ws + OPAR);
    float* cS   = ws + OCS;
    float* cY1  = ws + OCY1;
    float* cX1  = ws + OCX1;
    float* cY2  = ws + OCY2;
    float* cX2  = ws + OCX2;
    unsigned short* W2h = (unsigned short*)(ws + OW2H);
    unsigned short* W2l = (unsigned short*)(ws + OW2L);
    float* sY1  = ws + OSY1;
    float* sX1  = ws + OSX1;
    float* sY2  = ws + OSY2;
    float* sX2  = ws + OSX2;
    float* sAr  = ws + OSAR;
    unsigned long long* mask = (unsigned long long*)(ws + OMASK);

    float* out_scores = out;
    float* out_deltas = out + NBOX;
    float* out_props  = out + (size_t)NBOX * 5;

    hipMemsetAsync(hist, 0, (NHBINS + 8) * sizeof(unsigned int), stream);
    hipMemsetAsync(Xh, 0, 2 * NPAD * sizeof(unsigned short), stream);

    split_x<<<8000, 256, 0, stream>>>(X, Xh, Xl);
    split_w<<<576, 256, 0, stream>>>(W1, Wh, Wl);
    split_w2<<<96, 256, 0, stream>>>(Wc, Wr, W2h, W2l);

    conv_mfma<<<dim3(125, 4), 256, 0, stream>>>(Xh, Xl, Wh, Wl, b1, Yh, Yl);

    heads_mfma<<<125, 256, 0, stream>>>(Yh, Yl, W2h, W2l, bc, br, anch,
        out_scores, out_deltas, rawS, nmsS, pY1, pX1, pY2, pX2, hist);

    select_k<<<1, 1024, 0, stream>>>(hist, params);
    compact_k<<<(NBOX + 255) / 256, 256, 0, stream>>>(
        rawS, nmsS, pY1, pX1, pY2, pX2, params, cnts, cS, cY1, cX1, cY2, cX2);

    sort_k<<<1, 1024, 0, stream>>>(cS, cY1, cX1, cY2, cX2,
                                   sY1, sX1, sY2, sX2, sAr);
    mask_k<<<dim3(NWORDS, NWORDS), 64, 0, stream>>>(sY1, sX1, sY2, sX2, sAr, mask);
    scan2_k<<<1, 64, 0, stream>>>(sY1, sX1, sY2, sX2, mask, cnts, out_props);
}